// Round 7
// baseline (524.479 us; speedup 1.0000x reference)
//
#include <hip/hip_runtime.h>

// ---------------------------------------------------------------------------
// HeteroTripartiteGCN, round 16: slim intermediate records (8B -> 5B/edge).
//   r6 budget: total 489us, gather 119; bucketize+finesort ~220us combined,
//   dominated by uint2 recs traffic (68MB W + 2x68MB R). Changes:
//   - bucketize emits FINAL arena payload pay=(colp<<15)|val15 (colp includes
//     +NV/+NU unified-table shift via per-rel coladd) + 1-byte fine bin
//     binb=(row_local<<1)|srcflag. LDS-staged, coalesced stream-out
//     (dword-packed bytes with guarded tail: rel boundaries aren't 4-aligned).
//   - u/v buckets shrink to 128 rows (shift 7) so the bin fits a byte;
//     NB 666->1252; bucketize scan generalized to 3 bins/thread.
//   - finesort pass1 reads binb only (1B/edge), pass2 scatters pay verbatim.
//   - transforms, bscan, gather (pinned 4-deep pipeline) unchanged.
// d_out: [msg_u | msg_v | msg_f] fp32, every row written exactly once.
// ---------------------------------------------------------------------------

#define TDIM 64
#define EPB  4096

struct Rel {
    const int* rows; const int* cols; const float* vals;
    int n, chunk0, boff, shift, srcflag, eoff, coladd;
};
struct RelPack { Rel r[6]; };

struct TPack {
    const float* X[3]; const float* W1[3]; const float* W2[3];
    unsigned short* Y1[3]; unsigned short* Y2[3];
    int N[3]; int c0[3];
};

struct FSPack {              // per output type: the two source relations
    int c0A[3], cntA[3], offA[3];
    int c0B[3], cntB[3], offB[3];
};

struct GatherPack {
    const unsigned* srcA[3]; const unsigned* srcB[3];
    int n0, n1;   // NU, NU+NV
};

__device__ __forceinline__ unsigned short f2bf(float f) {
    union { float f; unsigned u; } c; c.f = f;
    unsigned r = c.u + 0x7FFFu + ((c.u >> 16) & 1u);  // RNE
    return (unsigned short)(r >> 16);
}
__device__ __forceinline__ float bflo(unsigned x) { return __uint_as_float(x << 16); }
__device__ __forceinline__ float bfhi(unsigned x) { return __uint_as_float(x & 0xFFFF0000u); }
__device__ __forceinline__ float pval(unsigned p) {
    return __uint_as_float((p & 0x7FFFu) << 16);     // bf16 val, sign==0
}

// ---------------- fused dense transforms (fp32 in, bf16 out) ----------------
__global__ __launch_bounds__(256) void transform_fused_kernel(TPack T)
{
    __shared__ float xsT[64 * 68];
    __shared__ float w1s[64 * 64];
    __shared__ float w2s[64 * 64];

    int t = 0;
    if ((int)blockIdx.x >= T.c0[1]) t = 1;
    if ((int)blockIdx.x >= T.c0[2]) t = 2;
    const float* __restrict__ X  = T.X[t];
    const float* __restrict__ W1 = T.W1[t];
    const float* __restrict__ W2 = T.W2[t];
    unsigned short* __restrict__ Y1 = T.Y1[t];
    unsigned short* __restrict__ Y2 = T.Y2[t];
    const int N    = T.N[t];
    const int row0 = (blockIdx.x - T.c0[t]) * 64;
    const int tid  = threadIdx.x;

    for (int i = tid * 4; i < 4096; i += 256 * 4) {
        *(float4*)&w1s[i] = *(const float4*)&W1[i];
        *(float4*)&w2s[i] = *(const float4*)&W2[i];
    }
    {
        const int r  = tid >> 2;
        const int c0 = (tid & 3) * 16;
        const int gr = row0 + r;
        #pragma unroll
        for (int cc = 0; cc < 16; cc += 4) {
            const int c = c0 + cc;
            float4 v = make_float4(0.f, 0.f, 0.f, 0.f);
            if (gr < N) v = *(const float4*)&X[(size_t)gr * TDIM + c];
            xsT[(c + 0) * 68 + r] = v.x;
            xsT[(c + 1) * 68 + r] = v.y;
            xsT[(c + 2) * 68 + r] = v.z;
            xsT[(c + 3) * 68 + r] = v.w;
        }
    }
    __syncthreads();

    const int tx = tid & 15;
    const int ty = tid >> 4;
    float a1[4][4] = {{0.f}}, a2[4][4] = {{0.f}};

    #pragma unroll 8
    for (int k = 0; k < 64; ++k) {
        const float4 xv = *(const float4*)&xsT[k * 68 + ty * 4];
        const float4 w1 = *(const float4*)&w1s[k * 64 + tx * 4];
        const float4 w2 = *(const float4*)&w2s[k * 64 + tx * 4];
        const float xr[4] = {xv.x, xv.y, xv.z, xv.w};
        const float c1[4] = {w1.x, w1.y, w1.z, w1.w};
        const float c2[4] = {w2.x, w2.y, w2.z, w2.w};
        #pragma unroll
        for (int r = 0; r < 4; ++r)
            #pragma unroll
            for (int c = 0; c < 4; ++c) {
                a1[r][c] = fmaf(xr[r], c1[c], a1[r][c]);
                a2[r][c] = fmaf(xr[r], c2[c], a2[r][c]);
            }
    }
    #pragma unroll
    for (int r = 0; r < 4; ++r) {
        const int gr = row0 + ty * 4 + r;
        if (gr < N) {
            ushort4 o1, o2;
            o1.x = f2bf(a1[r][0]); o1.y = f2bf(a1[r][1]);
            o1.z = f2bf(a1[r][2]); o1.w = f2bf(a1[r][3]);
            o2.x = f2bf(a2[r][0]); o2.y = f2bf(a2[r][1]);
            o2.z = f2bf(a2[r][2]); o2.w = f2bf(a2[r][3]);
            ((ushort4*)Y1)[(size_t)gr * 16 + tx] = o1;
            ((ushort4*)Y2)[(size_t)gr * 16 + tx] = o2;
        }
    }
}

__device__ __forceinline__ int find_rel(const RelPack& P, int chunk) {
    int ri = 0;
    if (chunk >= P.r[1].chunk0) ri = 1;
    if (chunk >= P.r[2].chunk0) ri = 2;
    if (chunk >= P.r[3].chunk0) ri = 3;
    if (chunk >= P.r[4].chunk0) ri = 4;
    if (chunk >= P.r[5].chunk0) ri = 5;
    return ri;
}

// ---------------- bucketize, chunk-major, LDS-staged, slim records ---------
// Pass A: read rows/cols once, park (bucket<<8|rowlocal) and colp in regs,
// LDS histogram. Scan (3 bins/thread, NB<=1280) -> localStart + cursors.
// Pass B: re-read vals (L3-hot), scatter pay/binb into LDS staging.
// Pass C: stream staging out coalesced (binb dword-packed, guarded tail).
__global__ __launch_bounds__(512) void bucketize_cm_kernel(
    RelPack P, unsigned* __restrict__ pay, unsigned char* __restrict__ binb,
    int* __restrict__ localStart, int* __restrict__ bucketTotal, int NB)
{
    __shared__ int cnt[1280];
    __shared__ int sh[512];
    __shared__ unsigned stage_pay[EPB];        // 16 KB
    __shared__ unsigned char stage_bin[EPB];   // 4 KB

    const int tid   = threadIdx.x;
    const int chunk = blockIdx.x;
    for (int t = tid; t < NB; t += 512) cnt[t] = 0;
    __syncthreads();

    const int ri = find_rel(P, chunk);
    const Rel M = P.r[ri];
    const int i0    = (chunk - M.chunk0) * EPB;
    const int rbase = M.eoff + i0;          // chunk's record segment base
    const int count = min(EPB, M.n - i0);   // valid records in this chunk

    const int mask = (1 << M.shift) - 1;
    const unsigned sf = (unsigned)M.srcflag;

    // pass A: histogram + park per-edge metadata in registers
    int      m_[EPB / 512];                 // (bucket<<8) | rowlocal, -1 invalid
    unsigned x_[EPB / 512];                 // colp (incl. coladd)
    #pragma unroll
    for (int k = 0; k < EPB / 512; ++k) {
        const int i = i0 + tid + k * 512;
        m_[k] = -1;
        if (i < M.n) {
            const int row = M.rows[i];
            const int b   = M.boff + (row >> M.shift);
            m_[k] = (b << 8) | (row & mask);
            x_[k] = (unsigned)M.cols[i] + (unsigned)M.coladd;
            atomicAdd(&cnt[b], 1);
        }
    }
    __syncthreads();

    // bucket totals + LDS exclusive scan, 3 bins/thread (NB <= 1536)
    int myv[3]; int lsum = 0;
    #pragma unroll
    for (int j = 0; j < 3; ++j) {
        const int idx = tid * 3 + j;
        myv[j] = (idx < NB) ? cnt[idx] : 0;
        lsum += myv[j];
    }
    sh[tid] = lsum;
    __syncthreads();
    for (int off = 1; off < 512; off <<= 1) {
        const int x = (tid >= off) ? sh[tid - off] : 0;
        __syncthreads();
        sh[tid] += x;
        __syncthreads();
    }
    int prefix = tid ? sh[tid - 1] : 0;
    const size_t lb = (size_t)chunk * (NB + 1);
    #pragma unroll
    for (int j = 0; j < 3; ++j) {
        const int idx = tid * 3 + j;
        if (idx < NB) {
            localStart[lb + idx] = prefix;
            if (myv[j]) atomicAdd(&bucketTotal[idx], myv[j]);
            cnt[idx] = prefix;              // cursor (bin owned by this thread)
        } else if (idx == NB) {
            localStart[lb + NB] = prefix;
        }
        prefix += myv[j];
    }
    __syncthreads();

    // pass B: re-read vals, scatter slim records into LDS staging
    #pragma unroll
    for (int k = 0; k < EPB / 512; ++k) {
        if (m_[k] >= 0) {
            const int i   = i0 + tid + k * 512;
            const int b   = m_[k] >> 8;
            const int pos = atomicAdd(&cnt[b], 1);
            stage_pay[pos] = (x_[k] << 15) | ((unsigned)f2bf(M.vals[i]) & 0x7FFFu);
            stage_bin[pos] = (unsigned char)(((m_[k] & 255) << 1) | sf);
        }
    }
    __syncthreads();

    // pass C: coalesced stream-out
    #pragma unroll
    for (int k = 0; k < EPB / 512; ++k) {
        const int j = tid + k * 512;
        if (j < count) pay[rbase + j] = stage_pay[j];
    }
    // binb: dword-packed; guard the tail (relation boundaries aren't 4-aligned,
    // an unguarded dword write would race with the neighboring chunk).
    {
        const int nfull = count >> 2;
        unsigned* bout = (unsigned*)(binb + rbase);      // rbase % 4 == 0
        const unsigned* bsrc = (const unsigned*)stage_bin;
        for (int j = tid; j < nfull; j += 512) bout[j] = bsrc[j];
        if (tid < (count & 3)) binb[rbase + nfull * 4 + tid] = stage_bin[nfull * 4 + tid];
    }
}

// ---------------- bscan: exclusive scan over NB buckets ----------------
__global__ __launch_bounds__(256) void bscan_kernel(
    const int* __restrict__ bucketTotal, int* __restrict__ bbase, int NB)
{
    __shared__ int sh[256];
    __shared__ int carry;
    const int t = threadIdx.x;
    if (t == 0) carry = 0;
    __syncthreads();
    for (int b0 = 0; b0 < NB; b0 += 256) {
        const int idx = b0 + t;
        const int c = (idx < NB) ? bucketTotal[idx] : 0;
        sh[t] = c;
        __syncthreads();
        for (int off = 1; off < 256; off <<= 1) {
            const int x = (t >= off) ? sh[t - off] : 0;
            __syncthreads();
            sh[t] += x;
            __syncthreads();
        }
        const int cbase = carry;
        if (idx < NB) bbase[idx] = cbase + sh[t] - c;
        __syncthreads();
        if (t == 0) carry = cbase + sh[255];
        __syncthreads();
    }
    if (t == 0) bbase[NB] = carry;
}

// ---------------- finesort: block per bucket over its runs ----------------
// pass1 reads 1B/edge (binb); pass2 reads binb+pay, scatters pay verbatim.
__global__ __launch_bounds__(512) void finesort_kernel(
    const unsigned* __restrict__ pay, const unsigned char* __restrict__ binb,
    const int* __restrict__ localStart, const int* __restrict__ bbase,
    FSPack F, int* __restrict__ p2, unsigned* __restrict__ arena,
    int nbU, int nbV, int NU, int NV, int NF, int NB, int ntot_rows)
{
    __shared__ int cnt[512];
    __shared__ int sh[512];
    __shared__ int runS[1024], runE[1024];

    const int b   = blockIdx.x;
    const int tid = threadIdx.x;

    int t, lb, rowbase;
    if (b < nbU)              { t = 0; lb = b;              rowbase = 0; }
    else if (b < nbU + nbV)   { t = 1; lb = b - nbU;        rowbase = NU; }
    else                      { t = 2; lb = b - nbU - nbV;  rowbase = NU + NV; }
    const int shift     = (t == 2) ? 6 : 7;
    const int Ntype     = (t == 0) ? NU : (t == 1) ? NV : NF;
    const int row_start = lb << shift;
    const int nrows     = min(1 << shift, Ntype - row_start);
    const int nbins     = (1 << shift) * 2;
    const int grow0     = rowbase + row_start;

    const int nA = F.cntA[t], nB_ = F.cntB[t];
    const int nRuns = nA + nB_;

    // load run directory into LDS (up to 1024 runs)
    for (int i = tid; i < nRuns; i += 512) {
        int c, base;
        if (i < nA) { c = F.c0A[t] + i;        base = F.offA[t] + i * EPB; }
        else        { int k = i - nA;
                      c = F.c0B[t] + k;        base = F.offB[t] + k * EPB; }
        const size_t lbi = (size_t)c * (NB + 1) + b;
        runS[i] = base + localStart[lbi];
        runE[i] = base + localStart[lbi + 1];
    }
    if (tid < nbins) cnt[tid] = 0;
    __syncthreads();

    const int s = bbase[b];
    const int e = bbase[b + 1];
    const int grp = tid >> 4;        // 32 groups of 16 lanes
    const int gl  = tid & 15;

    // pass 1: count fine bins (1B/edge)
    for (int ridx = grp; ridx < nRuns; ridx += 32) {
        const int rs = runS[ridx], re = runE[ridx];
        for (int j = rs + gl; j < re; j += 16) {
            atomicAdd(&cnt[binb[j]], 1);
        }
    }
    __syncthreads();

    // exclusive scan over nbins (<=256)
    const int v = (tid < nbins) ? cnt[tid] : 0;
    sh[tid] = v;
    __syncthreads();
    for (int off = 1; off < 512; off <<= 1) {
        const int x = (tid >= off) ? sh[tid - off] : 0;
        __syncthreads();
        sh[tid] += x;
        __syncthreads();
    }
    const int excl = sh[tid] - v;
    if (tid < nbins) cnt[tid] = excl;          // cursors
    if (tid < nrows * 2) p2[2 * grow0 + tid] = s + excl;
    if (b == NB - 1 && tid == 0) p2[2 * ntot_rows] = e;
    __syncthreads();

    // pass 2: scatter payload verbatim into bucket arena segment (L2-hot)
    for (int ridx = grp; ridx < nRuns; ridx += 32) {
        const int rs = runS[ridx], re = runE[ridx];
        for (int j = rs + gl; j < re; j += 16) {
            const int bin = binb[j];
            const int pos = s + atomicAdd(&cnt[bin], 1);
            arena[pos] = pay[j];
        }
    }
}

// ---------------- gather: wave/row, 8 lanes/edge, pinned 4-deep pipeline ---
__device__ __forceinline__ void accum_seg(
    const unsigned* __restrict__ src, const unsigned* __restrict__ arena,
    const int s, const int e, const int g, const int li4,
    float (&acc)[8])
{
    if (s >= e) return;
    const int nb = (e - s + 7) >> 3;
    const unsigned* __restrict__ srcp = src + li4;   // hoist lane offset

    unsigned x0[4], x1[4], x2[4], x3[4];
    float w0, w1, w2, w3;

    auto issue = [&](int j, unsigned* x, float& w) {
        const int idx = j + g;
        const bool ok = idx < e;
        const unsigned cv = arena[ok ? idx : s];      // clamped: always valid
        w = ok ? pval(cv) : 0.f;
        const uint4 xv = *(const uint4*)&srcp[(cv >> 15) * 32u];
        x[0] = xv.x; x[1] = xv.y; x[2] = xv.z; x[3] = xv.w;
    };
    auto fmab = [&](const unsigned* x, float w) {
        #pragma unroll
        for (int q = 0; q < 4; ++q) {
            acc[2 * q]     = fmaf(w, bflo(x[q]), acc[2 * q]);
            acc[2 * q + 1] = fmaf(w, bfhi(x[q]), acc[2 * q + 1]);
        }
    };

    issue(s,      x0, w0);
    issue(s + 8,  x1, w1);
    issue(s + 16, x2, w2);
    issue(s + 24, x3, w3);
    __builtin_amdgcn_sched_barrier(0);

    int k = 0;
    for (;;) {
        fmab(x0, w0);
        if (k + 4 < nb) issue(s + (k + 4) * 8, x0, w0);
        __builtin_amdgcn_sched_barrier(0);
        if (++k >= nb) break;
        fmab(x1, w1);
        if (k + 4 < nb) issue(s + (k + 4) * 8, x1, w1);
        __builtin_amdgcn_sched_barrier(0);
        if (++k >= nb) break;
        fmab(x2, w2);
        if (k + 4 < nb) issue(s + (k + 4) * 8, x2, w2);
        __builtin_amdgcn_sched_barrier(0);
        if (++k >= nb) break;
        fmab(x3, w3);
        if (k + 4 < nb) issue(s + (k + 4) * 8, x3, w3);
        __builtin_amdgcn_sched_barrier(0);
        if (++k >= nb) break;
    }
}

__global__ __launch_bounds__(256) void gather_all_kernel(
    const int* __restrict__ p2, const unsigned* __restrict__ arena,
    GatherPack G, float* __restrict__ out, int nrow_total)
{
    const int gid  = (blockIdx.x * 256 + threadIdx.x) >> 6;
    const int lane = threadIdx.x & 63;
    const int g    = lane >> 3;          // edge slot within block
    const int li   = lane & 7;           // component slice
    const int li4  = li * 4;             // u32 offset within row
    if (gid >= nrow_total) return;
    // reversed mapping: long f-rows (highest ids) launch first, short u-rows
    // fill the tail -> less end-of-grid imbalance.
    const int wid = nrow_total - 1 - gid;

    int seg = 0;
    if (wid >= G.n1)      seg = 2;
    else if (wid >= G.n0) seg = 1;
    seg = __builtin_amdgcn_readfirstlane(seg);

    const int pa = __builtin_amdgcn_readfirstlane(p2[2 * wid]);
    const int pe = __builtin_amdgcn_readfirstlane(p2[2 * wid + 2]);

    float acc[8];
    #pragma unroll
    for (int k = 0; k < 8; ++k) acc[k] = 0.f;

    if (seg < 2) {
        // unified table: single contiguous segment per row
        accum_seg(G.srcA[seg], arena, pa, pe, g, li4, acc);
    } else {
        const int pm = __builtin_amdgcn_readfirstlane(p2[2 * wid + 1]);
        accum_seg(G.srcA[2], arena, pa, pm, g, li4, acc);
        accum_seg(G.srcB[2], arena, pm, pe, g, li4, acc);
    }

    // reduce across the 8 edge-slot groups (lane bits 3,4,5)
    #pragma unroll
    for (int k = 0; k < 8; ++k) {
        acc[k] += __shfl_xor(acc[k], 8, 64);
        acc[k] += __shfl_xor(acc[k], 16, 64);
        acc[k] += __shfl_xor(acc[k], 32, 64);
    }

    if (g == 0) {
        float4 o0, o1;
        o0.x = fmaxf(acc[0], 0.f); o0.y = fmaxf(acc[1], 0.f);
        o0.z = fmaxf(acc[2], 0.f); o0.w = fmaxf(acc[3], 0.f);
        o1.x = fmaxf(acc[4], 0.f); o1.y = fmaxf(acc[5], 0.f);
        o1.z = fmaxf(acc[6], 0.f); o1.w = fmaxf(acc[7], 0.f);
        float4* dst = (float4*)(out + (size_t)wid * 64 + li * 8);
        dst[0] = o0;
        dst[1] = o1;
    }
}

// ---------------------------------------------------------------------------
extern "C" void kernel_launch(void* const* d_in, const int* in_sizes, int n_in,
                              void* d_out, int out_size, void* d_ws, size_t ws_size,
                              hipStream_t stream)
{
    const float* x_u    = (const float*)d_in[0];
    const float* x_v    = (const float*)d_in[1];
    const float* x_f    = (const float*)d_in[2];
    const float* W_u_uv = (const float*)d_in[3];
    const float* W_v_uv = (const float*)d_in[4];
    const float* W_f2u  = (const float*)d_in[5];
    const float* W_f2v  = (const float*)d_in[6];
    const float* W_u2f  = (const float*)d_in[7];
    const float* W_v2f  = (const float*)d_in[8];

    const int* rows_[6] = {(const int*)d_in[9],  (const int*)d_in[12],
                           (const int*)d_in[15], (const int*)d_in[18],
                           (const int*)d_in[21], (const int*)d_in[24]};
    const int* cols_[6] = {(const int*)d_in[10], (const int*)d_in[13],
                           (const int*)d_in[16], (const int*)d_in[19],
                           (const int*)d_in[22], (const int*)d_in[25]};
    const float* vals_[6] = {(const float*)d_in[11], (const float*)d_in[14],
                             (const float*)d_in[17], (const float*)d_in[20],
                             (const float*)d_in[23], (const float*)d_in[26]};

    const int NU = in_sizes[0] / TDIM;
    const int NV = in_sizes[1] / TDIM;
    const int NF = in_sizes[2] / TDIM;
    const int E_[6] = {in_sizes[9], in_sizes[12], in_sizes[15],
                       in_sizes[18], in_sizes[21], in_sizes[24]};

    const int nbU = (NU + 127) >> 7;
    const int nbV = (NV + 127) >> 7;
    const int nbF = (NF + 63) >> 6;
    const int NB  = nbU + nbV + nbF;
    const int ntot_rows = NU + NV + NF;

    // u: rel0 uv (A=tmp_v), rel2 uf (B=f2u -> colp += NV)
    // v: rel1 vu (A=tmp_u), rel3 vf (B=f2v -> colp += NU)
    // f: rel4 fu (A=u2f),  rel5 fv (B=v2f)
    const int boff_[6]   = {0, nbU, 0, nbU, nbU + nbV, nbU + nbV};
    const int shift_[6]  = {7, 7, 7, 7, 6, 6};
    const int sflag_[6]  = {0, 0, 1, 1, 0, 1};
    const int coladd_[6] = {0, 0, NV, NU, 0, 0};

    size_t etot = 0;
    int eoff_[6];
    for (int r = 0; r < 6; ++r) { eoff_[r] = (int)etot; etot += (size_t)E_[r]; }

    // ---- relation pack / chunk map ----
    RelPack P;
    int nchunks = 0;
    int relchunks[6];
    for (int r = 0; r < 6; ++r) {
        P.r[r].rows = rows_[r]; P.r[r].cols = cols_[r]; P.r[r].vals = vals_[r];
        P.r[r].n = E_[r]; P.r[r].chunk0 = nchunks;
        P.r[r].boff = boff_[r]; P.r[r].shift = shift_[r]; P.r[r].srcflag = sflag_[r];
        P.r[r].eoff = eoff_[r]; P.r[r].coladd = coladd_[r];
        relchunks[r] = (E_[r] + EPB - 1) / EPB;
        nchunks += relchunks[r];
    }

    // ---- workspace ----
    char* wsb = (char*)d_ws;
    size_t o = 0;
    auto alloc = [&](size_t bytes) {
        char* p = wsb + o;
        o = (o + bytes + 15) & ~(size_t)15;
        return p;
    };
    // unified tables: [tmp_v | f2u] for u-gather, [tmp_u | f2v] for v-gather
    unsigned short* utab = (unsigned short*)alloc(((size_t)NV + NF) * TDIM * 2);
    unsigned short* vtab = (unsigned short*)alloc(((size_t)NU + NF) * TDIM * 2);
    unsigned short* u2f  = (unsigned short*)alloc((size_t)NU * TDIM * 2);
    unsigned short* v2f  = (unsigned short*)alloc((size_t)NV * TDIM * 2);
    unsigned short* tmp_v = utab;
    unsigned short* f2u   = utab + (size_t)NV * TDIM;
    unsigned short* tmp_u = vtab;
    unsigned short* f2v   = vtab + (size_t)NU * TDIM;
    int* localStart  = (int*)alloc((size_t)nchunks * (NB + 1) * 4);
    int* bucketTotal = (int*)alloc((size_t)NB * 4);
    int* bbase       = (int*)alloc((size_t)(NB + 1) * 4);
    int* p2          = (int*)alloc((size_t)(2 * ntot_rows + 1) * 4);
    unsigned* pay        = (unsigned*)alloc(etot * 4);
    unsigned char* binb  = (unsigned char*)alloc(etot);
    unsigned* arena      = (unsigned*)alloc(etot * 4);
    (void)ws_size;

    // ---- fused transforms ----
    TPack T;
    T.X[0] = x_u; T.W1[0] = W_u_uv; T.W2[0] = W_u2f; T.Y1[0] = tmp_u; T.Y2[0] = u2f; T.N[0] = NU;
    T.X[1] = x_v; T.W1[1] = W_v_uv; T.W2[1] = W_v2f; T.Y1[1] = tmp_v; T.Y2[1] = v2f; T.N[1] = NV;
    T.X[2] = x_f; T.W1[2] = W_f2u;  T.W2[2] = W_f2v; T.Y1[2] = f2u;  T.Y2[2] = f2v; T.N[2] = NF;
    T.c0[0] = 0;
    T.c0[1] = (NU + 63) / 64;
    T.c0[2] = T.c0[1] + (NV + 63) / 64;
    const int tchunks = T.c0[2] + (NF + 63) / 64;
    transform_fused_kernel<<<tchunks, 256, 0, stream>>>(T);

    // ---- sort pipeline ----
    hipMemsetAsync(bucketTotal, 0, (size_t)NB * sizeof(int), stream);
    bucketize_cm_kernel<<<nchunks, 512, 0, stream>>>(P, pay, binb, localStart, bucketTotal, NB);
    bscan_kernel<<<1, 256, 0, stream>>>(bucketTotal, bbase, NB);

    FSPack F;
    const int Arel[3] = {0, 1, 4}, Brel[3] = {2, 3, 5};
    for (int t = 0; t < 3; ++t) {
        F.c0A[t] = P.r[Arel[t]].chunk0; F.cntA[t] = relchunks[Arel[t]]; F.offA[t] = eoff_[Arel[t]];
        F.c0B[t] = P.r[Brel[t]].chunk0; F.cntB[t] = relchunks[Brel[t]]; F.offB[t] = eoff_[Brel[t]];
    }
    finesort_kernel<<<NB, 512, 0, stream>>>(
        pay, binb, localStart, bbase, F, p2, arena, nbU, nbV, NU, NV, NF, NB, ntot_rows);

    // ---- gather (+ReLU) ----
    GatherPack G;
    G.srcA[0] = (const unsigned*)utab;  G.srcB[0] = (const unsigned*)utab;  // unified
    G.srcA[1] = (const unsigned*)vtab;  G.srcB[1] = (const unsigned*)vtab;  // unified
    G.srcA[2] = (const unsigned*)u2f;   G.srcB[2] = (const unsigned*)v2f;
    G.n0 = NU; G.n1 = NU + NV;

    gather_all_kernel<<<(ntot_rows + 3) / 4, 256, 0, stream>>>(
        p2, arena, G, (float*)d_out, ntot_rows);
}

// Round 8
// 512.499 us; speedup vs baseline: 1.0234x; 1.0234x over previous
//
#include <hip/hip_runtime.h>

// ---------------------------------------------------------------------------
// HeteroTripartiteGCN, round 17: finesort LDS-staged arena + transposed dir.
//   r7 rocprof: finesort 131us, WRITE 125.7MB (3.6x amp: 4B atomic scatter),
//   FETCH 144.6MB (strided localStart reads: 64B line per 4B used).
//   Fixes (same medicine that fixed bucketize in r14):
//   - pass2 scatters pay into a 40KB LDS segment buffer (relative cursors),
//     pass3 streams it to arena coalesced (1x write amp). f-buckets shrink
//     to 32 rows (shift 5) so segments fit 10240 cap; block-uniform direct-
//     scatter fallback if a segment ever exceeds the cap.
//   - new transpose_ls kernel: localStart[chunk][bucket] -> TL[bucket][chunk]
//     so finesort reads its run directory as two contiguous streams.
//   Everything else unchanged from r16 (slim 5B records, LDS-staged
//   bucketize, unified u/v tables, pinned 4-deep gather pipeline).
// d_out: [msg_u | msg_v | msg_f] fp32, every row written exactly once.
// ---------------------------------------------------------------------------

#define TDIM 64
#define EPB  4096
#define STCAP 10240   // finesort LDS segment capacity (40KB)

struct Rel {
    const int* rows; const int* cols; const float* vals;
    int n, chunk0, boff, shift, srcflag, eoff, coladd;
};
struct RelPack { Rel r[6]; };

struct TPack {
    const float* X[3]; const float* W1[3]; const float* W2[3];
    unsigned short* Y1[3]; unsigned short* Y2[3];
    int N[3]; int c0[3];
};

struct FSPack {              // per output type: the two source relations
    int c0A[3], cntA[3], offA[3];
    int c0B[3], cntB[3], offB[3];
};

struct GatherPack {
    const unsigned* srcA[3]; const unsigned* srcB[3];
    int n0, n1;   // NU, NU+NV
};

__device__ __forceinline__ unsigned short f2bf(float f) {
    union { float f; unsigned u; } c; c.f = f;
    unsigned r = c.u + 0x7FFFu + ((c.u >> 16) & 1u);  // RNE
    return (unsigned short)(r >> 16);
}
__device__ __forceinline__ float bflo(unsigned x) { return __uint_as_float(x << 16); }
__device__ __forceinline__ float bfhi(unsigned x) { return __uint_as_float(x & 0xFFFF0000u); }
__device__ __forceinline__ float pval(unsigned p) {
    return __uint_as_float((p & 0x7FFFu) << 16);     // bf16 val, sign==0
}

// ---------------- fused dense transforms (fp32 in, bf16 out) ----------------
__global__ __launch_bounds__(256) void transform_fused_kernel(TPack T)
{
    __shared__ float xsT[64 * 68];
    __shared__ float w1s[64 * 64];
    __shared__ float w2s[64 * 64];

    int t = 0;
    if ((int)blockIdx.x >= T.c0[1]) t = 1;
    if ((int)blockIdx.x >= T.c0[2]) t = 2;
    const float* __restrict__ X  = T.X[t];
    const float* __restrict__ W1 = T.W1[t];
    const float* __restrict__ W2 = T.W2[t];
    unsigned short* __restrict__ Y1 = T.Y1[t];
    unsigned short* __restrict__ Y2 = T.Y2[t];
    const int N    = T.N[t];
    const int row0 = (blockIdx.x - T.c0[t]) * 64;
    const int tid  = threadIdx.x;

    for (int i = tid * 4; i < 4096; i += 256 * 4) {
        *(float4*)&w1s[i] = *(const float4*)&W1[i];
        *(float4*)&w2s[i] = *(const float4*)&W2[i];
    }
    {
        const int r  = tid >> 2;
        const int c0 = (tid & 3) * 16;
        const int gr = row0 + r;
        #pragma unroll
        for (int cc = 0; cc < 16; cc += 4) {
            const int c = c0 + cc;
            float4 v = make_float4(0.f, 0.f, 0.f, 0.f);
            if (gr < N) v = *(const float4*)&X[(size_t)gr * TDIM + c];
            xsT[(c + 0) * 68 + r] = v.x;
            xsT[(c + 1) * 68 + r] = v.y;
            xsT[(c + 2) * 68 + r] = v.z;
            xsT[(c + 3) * 68 + r] = v.w;
        }
    }
    __syncthreads();

    const int tx = tid & 15;
    const int ty = tid >> 4;
    float a1[4][4] = {{0.f}}, a2[4][4] = {{0.f}};

    #pragma unroll 8
    for (int k = 0; k < 64; ++k) {
        const float4 xv = *(const float4*)&xsT[k * 68 + ty * 4];
        const float4 w1 = *(const float4*)&w1s[k * 64 + tx * 4];
        const float4 w2 = *(const float4*)&w2s[k * 64 + tx * 4];
        const float xr[4] = {xv.x, xv.y, xv.z, xv.w};
        const float c1[4] = {w1.x, w1.y, w1.z, w1.w};
        const float c2[4] = {w2.x, w2.y, w2.z, w2.w};
        #pragma unroll
        for (int r = 0; r < 4; ++r)
            #pragma unroll
            for (int c = 0; c < 4; ++c) {
                a1[r][c] = fmaf(xr[r], c1[c], a1[r][c]);
                a2[r][c] = fmaf(xr[r], c2[c], a2[r][c]);
            }
    }
    #pragma unroll
    for (int r = 0; r < 4; ++r) {
        const int gr = row0 + ty * 4 + r;
        if (gr < N) {
            ushort4 o1, o2;
            o1.x = f2bf(a1[r][0]); o1.y = f2bf(a1[r][1]);
            o1.z = f2bf(a1[r][2]); o1.w = f2bf(a1[r][3]);
            o2.x = f2bf(a2[r][0]); o2.y = f2bf(a2[r][1]);
            o2.z = f2bf(a2[r][2]); o2.w = f2bf(a2[r][3]);
            ((ushort4*)Y1)[(size_t)gr * 16 + tx] = o1;
            ((ushort4*)Y2)[(size_t)gr * 16 + tx] = o2;
        }
    }
}

__device__ __forceinline__ int find_rel(const RelPack& P, int chunk) {
    int ri = 0;
    if (chunk >= P.r[1].chunk0) ri = 1;
    if (chunk >= P.r[2].chunk0) ri = 2;
    if (chunk >= P.r[3].chunk0) ri = 3;
    if (chunk >= P.r[4].chunk0) ri = 4;
    if (chunk >= P.r[5].chunk0) ri = 5;
    return ri;
}

// ---------------- bucketize, chunk-major, LDS-staged, slim records ---------
__global__ __launch_bounds__(512) void bucketize_cm_kernel(
    RelPack P, unsigned* __restrict__ pay, unsigned char* __restrict__ binb,
    int* __restrict__ localStart, int* __restrict__ bucketTotal, int NB)
{
    __shared__ int cnt[1536];
    __shared__ int sh[512];
    __shared__ unsigned stage_pay[EPB];        // 16 KB
    __shared__ unsigned char stage_bin[EPB];   // 4 KB

    const int tid   = threadIdx.x;
    const int chunk = blockIdx.x;
    for (int t = tid; t < NB; t += 512) cnt[t] = 0;
    __syncthreads();

    const int ri = find_rel(P, chunk);
    const Rel M = P.r[ri];
    const int i0    = (chunk - M.chunk0) * EPB;
    const int rbase = M.eoff + i0;          // chunk's record segment base
    const int count = min(EPB, M.n - i0);   // valid records in this chunk

    const int mask = (1 << M.shift) - 1;
    const unsigned sf = (unsigned)M.srcflag;

    // pass A: histogram + park per-edge metadata in registers
    int      m_[EPB / 512];                 // (bucket<<8) | rowlocal, -1 invalid
    unsigned x_[EPB / 512];                 // colp (incl. coladd)
    #pragma unroll
    for (int k = 0; k < EPB / 512; ++k) {
        const int i = i0 + tid + k * 512;
        m_[k] = -1;
        if (i < M.n) {
            const int row = M.rows[i];
            const int b   = M.boff + (row >> M.shift);
            m_[k] = (b << 8) | (row & mask);
            x_[k] = (unsigned)M.cols[i] + (unsigned)M.coladd;
            atomicAdd(&cnt[b], 1);
        }
    }
    __syncthreads();

    // bucket totals + LDS exclusive scan, 3 bins/thread (NB <= 1536)
    int myv[3]; int lsum = 0;
    #pragma unroll
    for (int j = 0; j < 3; ++j) {
        const int idx = tid * 3 + j;
        myv[j] = (idx < NB) ? cnt[idx] : 0;
        lsum += myv[j];
    }
    sh[tid] = lsum;
    __syncthreads();
    for (int off = 1; off < 512; off <<= 1) {
        const int x = (tid >= off) ? sh[tid - off] : 0;
        __syncthreads();
        sh[tid] += x;
        __syncthreads();
    }
    int prefix = tid ? sh[tid - 1] : 0;
    const size_t lb = (size_t)chunk * (NB + 1);
    #pragma unroll
    for (int j = 0; j < 3; ++j) {
        const int idx = tid * 3 + j;
        if (idx < NB) {
            localStart[lb + idx] = prefix;
            if (myv[j]) atomicAdd(&bucketTotal[idx], myv[j]);
            cnt[idx] = prefix;              // cursor
        } else if (idx == NB) {
            localStart[lb + NB] = prefix;
        }
        prefix += myv[j];
    }
    __syncthreads();

    // pass B: re-read vals, scatter slim records into LDS staging
    #pragma unroll
    for (int k = 0; k < EPB / 512; ++k) {
        if (m_[k] >= 0) {
            const int i   = i0 + tid + k * 512;
            const int b   = m_[k] >> 8;
            const int pos = atomicAdd(&cnt[b], 1);
            stage_pay[pos] = (x_[k] << 15) | ((unsigned)f2bf(M.vals[i]) & 0x7FFFu);
            stage_bin[pos] = (unsigned char)(((m_[k] & 255) << 1) | sf);
        }
    }
    __syncthreads();

    // pass C: coalesced stream-out
    #pragma unroll
    for (int k = 0; k < EPB / 512; ++k) {
        const int j = tid + k * 512;
        if (j < count) pay[rbase + j] = stage_pay[j];
    }
    // binb: dword-packed; guarded tail (rel boundaries aren't 4-aligned)
    {
        const int nfull = count >> 2;
        unsigned* bout = (unsigned*)(binb + rbase);      // rbase % 4 == 0
        const unsigned* bsrc = (const unsigned*)stage_bin;
        for (int j = tid; j < nfull; j += 512) bout[j] = bsrc[j];
        if (tid < (count & 3)) binb[rbase + nfull * 4 + tid] = stage_bin[nfull * 4 + tid];
    }
}

// ---------------- transpose_ls: localStart[chunk][.] -> TL[.][chunk] -------
__global__ __launch_bounds__(256) void transpose_ls_kernel(
    const int* __restrict__ src, int* __restrict__ dst, int rows, int cols)
{   // src[r][c] (row stride cols) -> dst[c][r] (row stride rows)
    __shared__ int tile[32][33];
    const int c0 = blockIdx.x * 32;
    const int r0 = blockIdx.y * 32;
    const int tx = threadIdx.x & 31;
    const int ty = threadIdx.x >> 5;     // 0..7
    #pragma unroll
    for (int k = 0; k < 32; k += 8) {
        const int r = r0 + ty + k, c = c0 + tx;
        if (r < rows && c < cols) tile[ty + k][tx] = src[(size_t)r * cols + c];
    }
    __syncthreads();
    #pragma unroll
    for (int k = 0; k < 32; k += 8) {
        const int c = c0 + ty + k, r = r0 + tx;
        if (c < cols && r < rows) dst[(size_t)c * rows + r] = tile[tx][ty + k];
    }
}

// ---------------- bscan: exclusive scan over NB buckets ----------------
__global__ __launch_bounds__(256) void bscan_kernel(
    const int* __restrict__ bucketTotal, int* __restrict__ bbase, int NB)
{
    __shared__ int sh[256];
    __shared__ int carry;
    const int t = threadIdx.x;
    if (t == 0) carry = 0;
    __syncthreads();
    for (int b0 = 0; b0 < NB; b0 += 256) {
        const int idx = b0 + t;
        const int c = (idx < NB) ? bucketTotal[idx] : 0;
        sh[t] = c;
        __syncthreads();
        for (int off = 1; off < 256; off <<= 1) {
            const int x = (t >= off) ? sh[t - off] : 0;
            __syncthreads();
            sh[t] += x;
            __syncthreads();
        }
        const int cbase = carry;
        if (idx < NB) bbase[idx] = cbase + sh[t] - c;
        __syncthreads();
        if (t == 0) carry = cbase + sh[255];
        __syncthreads();
    }
    if (t == 0) bbase[NB] = carry;
}

// ---------------- finesort: block per bucket, LDS-staged arena segment ----
__global__ __launch_bounds__(512) void finesort_kernel(
    const unsigned* __restrict__ pay, const unsigned char* __restrict__ binb,
    const int* __restrict__ TL, const int* __restrict__ bbase,
    FSPack F, int* __restrict__ p2, unsigned* __restrict__ arena,
    int nbU, int nbV, int NU, int NV, int NF, int NB, int ntot_rows,
    int nchunksTot)
{
    __shared__ int cnt[512];
    __shared__ int sh[512];
    __shared__ int runS[1024], runE[1024];
    __shared__ unsigned stage[STCAP];    // 40 KB

    const int b   = blockIdx.x;
    const int tid = threadIdx.x;

    int t, lb, rowbase;
    if (b < nbU)              { t = 0; lb = b;              rowbase = 0; }
    else if (b < nbU + nbV)   { t = 1; lb = b - nbU;        rowbase = NU; }
    else                      { t = 2; lb = b - nbU - nbV;  rowbase = NU + NV; }
    const int shift     = (t == 2) ? 5 : 7;
    const int Ntype     = (t == 0) ? NU : (t == 1) ? NV : NF;
    const int row_start = lb << shift;
    const int nrows     = min(1 << shift, Ntype - row_start);
    const int nbins     = (1 << shift) * 2;
    const int grow0     = rowbase + row_start;

    const int nA = F.cntA[t], nB_ = F.cntB[t];
    const int nRuns = nA + nB_;

    // run directory: TL[b][chunk] and TL[b+1][chunk] are contiguous streams
    const int* __restrict__ TLb  = TL + (size_t)b * nchunksTot;
    const int* __restrict__ TLb1 = TL + (size_t)(b + 1) * nchunksTot;
    for (int i = tid; i < nRuns; i += 512) {
        int ci, base;
        if (i < nA) { ci = F.c0A[t] + i;        base = F.offA[t] + i * EPB; }
        else        { int k = i - nA;
                      ci = F.c0B[t] + k;        base = F.offB[t] + k * EPB; }
        runS[i] = base + TLb[ci];
        runE[i] = base + TLb1[ci];
    }
    if (tid < nbins) cnt[tid] = 0;
    __syncthreads();

    const int s = bbase[b];
    const int e = bbase[b + 1];
    const bool staged = (e - s) <= STCAP;
    const int grp = tid >> 4;        // 32 groups of 16 lanes
    const int gl  = tid & 15;

    // pass 1: count fine bins (1B/edge)
    for (int ridx = grp; ridx < nRuns; ridx += 32) {
        const int rs = runS[ridx], re = runE[ridx];
        for (int j = rs + gl; j < re; j += 16) {
            atomicAdd(&cnt[binb[j]], 1);
        }
    }
    __syncthreads();

    // exclusive scan over nbins (<=256)
    const int v = (tid < nbins) ? cnt[tid] : 0;
    sh[tid] = v;
    __syncthreads();
    for (int off = 1; off < 512; off <<= 1) {
        const int x = (tid >= off) ? sh[tid - off] : 0;
        __syncthreads();
        sh[tid] += x;
        __syncthreads();
    }
    const int excl = sh[tid] - v;
    if (tid < nbins) cnt[tid] = staged ? excl : (s + excl);   // cursors
    if (tid < nrows * 2) p2[2 * grow0 + tid] = s + excl;
    if (b == NB - 1 && tid == 0) p2[2 * ntot_rows] = e;
    __syncthreads();

    if (staged) {
        // pass 2: scatter payload into LDS segment (relative positions)
        for (int ridx = grp; ridx < nRuns; ridx += 32) {
            const int rs = runS[ridx], re = runE[ridx];
            for (int j = rs + gl; j < re; j += 16) {
                const int pos = atomicAdd(&cnt[binb[j]], 1);
                stage[pos] = pay[j];
            }
        }
        __syncthreads();
        // pass 3: coalesced stream-out of the bucket segment
        const int seglen = e - s;
        for (int j = tid; j < seglen; j += 512) arena[s + j] = stage[j];
    } else {
        // fallback (not expected at these sizes): direct global scatter
        for (int ridx = grp; ridx < nRuns; ridx += 32) {
            const int rs = runS[ridx], re = runE[ridx];
            for (int j = rs + gl; j < re; j += 16) {
                const int pos = atomicAdd(&cnt[binb[j]], 1);
                arena[pos] = pay[j];
            }
        }
    }
}

// ---------------- gather: wave/row, 8 lanes/edge, pinned 4-deep pipeline ---
__device__ __forceinline__ void accum_seg(
    const unsigned* __restrict__ src, const unsigned* __restrict__ arena,
    const int s, const int e, const int g, const int li4,
    float (&acc)[8])
{
    if (s >= e) return;
    const int nb = (e - s + 7) >> 3;
    const unsigned* __restrict__ srcp = src + li4;   // hoist lane offset

    unsigned x0[4], x1[4], x2[4], x3[4];
    float w0, w1, w2, w3;

    auto issue = [&](int j, unsigned* x, float& w) {
        const int idx = j + g;
        const bool ok = idx < e;
        const unsigned cv = arena[ok ? idx : s];      // clamped: always valid
        w = ok ? pval(cv) : 0.f;
        const uint4 xv = *(const uint4*)&srcp[(cv >> 15) * 32u];
        x[0] = xv.x; x[1] = xv.y; x[2] = xv.z; x[3] = xv.w;
    };
    auto fmab = [&](const unsigned* x, float w) {
        #pragma unroll
        for (int q = 0; q < 4; ++q) {
            acc[2 * q]     = fmaf(w, bflo(x[q]), acc[2 * q]);
            acc[2 * q + 1] = fmaf(w, bfhi(x[q]), acc[2 * q + 1]);
        }
    };

    issue(s,      x0, w0);
    issue(s + 8,  x1, w1);
    issue(s + 16, x2, w2);
    issue(s + 24, x3, w3);
    __builtin_amdgcn_sched_barrier(0);

    int k = 0;
    for (;;) {
        fmab(x0, w0);
        if (k + 4 < nb) issue(s + (k + 4) * 8, x0, w0);
        __builtin_amdgcn_sched_barrier(0);
        if (++k >= nb) break;
        fmab(x1, w1);
        if (k + 4 < nb) issue(s + (k + 4) * 8, x1, w1);
        __builtin_amdgcn_sched_barrier(0);
        if (++k >= nb) break;
        fmab(x2, w2);
        if (k + 4 < nb) issue(s + (k + 4) * 8, x2, w2);
        __builtin_amdgcn_sched_barrier(0);
        if (++k >= nb) break;
        fmab(x3, w3);
        if (k + 4 < nb) issue(s + (k + 4) * 8, x3, w3);
        __builtin_amdgcn_sched_barrier(0);
        if (++k >= nb) break;
    }
}

__global__ __launch_bounds__(256) void gather_all_kernel(
    const int* __restrict__ p2, const unsigned* __restrict__ arena,
    GatherPack G, float* __restrict__ out, int nrow_total)
{
    const int gid  = (blockIdx.x * 256 + threadIdx.x) >> 6;
    const int lane = threadIdx.x & 63;
    const int g    = lane >> 3;          // edge slot within block
    const int li   = lane & 7;           // component slice
    const int li4  = li * 4;             // u32 offset within row
    if (gid >= nrow_total) return;
    const int wid = nrow_total - 1 - gid;   // long f-rows first

    int seg = 0;
    if (wid >= G.n1)      seg = 2;
    else if (wid >= G.n0) seg = 1;
    seg = __builtin_amdgcn_readfirstlane(seg);

    const int pa = __builtin_amdgcn_readfirstlane(p2[2 * wid]);
    const int pe = __builtin_amdgcn_readfirstlane(p2[2 * wid + 2]);

    float acc[8];
    #pragma unroll
    for (int k = 0; k < 8; ++k) acc[k] = 0.f;

    if (seg < 2) {
        accum_seg(G.srcA[seg], arena, pa, pe, g, li4, acc);
    } else {
        const int pm = __builtin_amdgcn_readfirstlane(p2[2 * wid + 1]);
        accum_seg(G.srcA[2], arena, pa, pm, g, li4, acc);
        accum_seg(G.srcB[2], arena, pm, pe, g, li4, acc);
    }

    #pragma unroll
    for (int k = 0; k < 8; ++k) {
        acc[k] += __shfl_xor(acc[k], 8, 64);
        acc[k] += __shfl_xor(acc[k], 16, 64);
        acc[k] += __shfl_xor(acc[k], 32, 64);
    }

    if (g == 0) {
        float4 o0, o1;
        o0.x = fmaxf(acc[0], 0.f); o0.y = fmaxf(acc[1], 0.f);
        o0.z = fmaxf(acc[2], 0.f); o0.w = fmaxf(acc[3], 0.f);
        o1.x = fmaxf(acc[4], 0.f); o1.y = fmaxf(acc[5], 0.f);
        o1.z = fmaxf(acc[6], 0.f); o1.w = fmaxf(acc[7], 0.f);
        float4* dst = (float4*)(out + (size_t)wid * 64 + li * 8);
        dst[0] = o0;
        dst[1] = o1;
    }
}

// ---------------------------------------------------------------------------
extern "C" void kernel_launch(void* const* d_in, const int* in_sizes, int n_in,
                              void* d_out, int out_size, void* d_ws, size_t ws_size,
                              hipStream_t stream)
{
    const float* x_u    = (const float*)d_in[0];
    const float* x_v    = (const float*)d_in[1];
    const float* x_f    = (const float*)d_in[2];
    const float* W_u_uv = (const float*)d_in[3];
    const float* W_v_uv = (const float*)d_in[4];
    const float* W_f2u  = (const float*)d_in[5];
    const float* W_f2v  = (const float*)d_in[6];
    const float* W_u2f  = (const float*)d_in[7];
    const float* W_v2f  = (const float*)d_in[8];

    const int* rows_[6] = {(const int*)d_in[9],  (const int*)d_in[12],
                           (const int*)d_in[15], (const int*)d_in[18],
                           (const int*)d_in[21], (const int*)d_in[24]};
    const int* cols_[6] = {(const int*)d_in[10], (const int*)d_in[13],
                           (const int*)d_in[16], (const int*)d_in[19],
                           (const int*)d_in[22], (const int*)d_in[25]};
    const float* vals_[6] = {(const float*)d_in[11], (const float*)d_in[14],
                             (const float*)d_in[17], (const float*)d_in[20],
                             (const float*)d_in[23], (const float*)d_in[26]};

    const int NU = in_sizes[0] / TDIM;
    const int NV = in_sizes[1] / TDIM;
    const int NF = in_sizes[2] / TDIM;
    const int E_[6] = {in_sizes[9], in_sizes[12], in_sizes[15],
                       in_sizes[18], in_sizes[21], in_sizes[24]};

    const int nbU = (NU + 127) >> 7;
    const int nbV = (NV + 127) >> 7;
    const int nbF = (NF + 31) >> 5;
    const int NB  = nbU + nbV + nbF;
    const int ntot_rows = NU + NV + NF;

    // u: rel0 uv (A=tmp_v), rel2 uf (B=f2u -> colp += NV)
    // v: rel1 vu (A=tmp_u), rel3 vf (B=f2v -> colp += NU)
    // f: rel4 fu (A=u2f),  rel5 fv (B=v2f)
    const int boff_[6]   = {0, nbU, 0, nbU, nbU + nbV, nbU + nbV};
    const int shift_[6]  = {7, 7, 7, 7, 5, 5};
    const int sflag_[6]  = {0, 0, 1, 1, 0, 1};
    const int coladd_[6] = {0, 0, NV, NU, 0, 0};

    size_t etot = 0;
    int eoff_[6];
    for (int r = 0; r < 6; ++r) { eoff_[r] = (int)etot; etot += (size_t)E_[r]; }

    // ---- relation pack / chunk map ----
    RelPack P;
    int nchunks = 0;
    int relchunks[6];
    for (int r = 0; r < 6; ++r) {
        P.r[r].rows = rows_[r]; P.r[r].cols = cols_[r]; P.r[r].vals = vals_[r];
        P.r[r].n = E_[r]; P.r[r].chunk0 = nchunks;
        P.r[r].boff = boff_[r]; P.r[r].shift = shift_[r]; P.r[r].srcflag = sflag_[r];
        P.r[r].eoff = eoff_[r]; P.r[r].coladd = coladd_[r];
        relchunks[r] = (E_[r] + EPB - 1) / EPB;
        nchunks += relchunks[r];
    }

    // ---- workspace ----
    char* wsb = (char*)d_ws;
    size_t o = 0;
    auto alloc = [&](size_t bytes) {
        char* p = wsb + o;
        o = (o + bytes + 15) & ~(size_t)15;
        return p;
    };
    // unified tables: [tmp_v | f2u] for u-gather, [tmp_u | f2v] for v-gather
    unsigned short* utab = (unsigned short*)alloc(((size_t)NV + NF) * TDIM * 2);
    unsigned short* vtab = (unsigned short*)alloc(((size_t)NU + NF) * TDIM * 2);
    unsigned short* u2f  = (unsigned short*)alloc((size_t)NU * TDIM * 2);
    unsigned short* v2f  = (unsigned short*)alloc((size_t)NV * TDIM * 2);
    unsigned short* tmp_v = utab;
    unsigned short* f2u   = utab + (size_t)NV * TDIM;
    unsigned short* tmp_u = vtab;
    unsigned short* f2v   = vtab + (size_t)NU * TDIM;
    int* localStart  = (int*)alloc((size_t)nchunks * (NB + 1) * 4);
    int* TL          = (int*)alloc((size_t)(NB + 1) * nchunks * 4);
    int* bucketTotal = (int*)alloc((size_t)NB * 4);
    int* bbase       = (int*)alloc((size_t)(NB + 1) * 4);
    int* p2          = (int*)alloc((size_t)(2 * ntot_rows + 1) * 4);
    unsigned* pay        = (unsigned*)alloc(etot * 4);
    unsigned char* binb  = (unsigned char*)alloc(etot);
    unsigned* arena      = (unsigned*)alloc(etot * 4);
    (void)ws_size;

    // ---- fused transforms ----
    TPack T;
    T.X[0] = x_u; T.W1[0] = W_u_uv; T.W2[0] = W_u2f; T.Y1[0] = tmp_u; T.Y2[0] = u2f; T.N[0] = NU;
    T.X[1] = x_v; T.W1[1] = W_v_uv; T.W2[1] = W_v2f; T.Y1[1] = tmp_v; T.Y2[1] = v2f; T.N[1] = NV;
    T.X[2] = x_f; T.W1[2] = W_f2u;  T.W2[2] = W_f2v; T.Y1[2] = f2u;  T.Y2[2] = f2v; T.N[2] = NF;
    T.c0[0] = 0;
    T.c0[1] = (NU + 63) / 64;
    T.c0[2] = T.c0[1] + (NV + 63) / 64;
    const int tchunks = T.c0[2] + (NF + 63) / 64;
    transform_fused_kernel<<<tchunks, 256, 0, stream>>>(T);

    // ---- sort pipeline ----
    hipMemsetAsync(bucketTotal, 0, (size_t)NB * sizeof(int), stream);
    bucketize_cm_kernel<<<nchunks, 512, 0, stream>>>(P, pay, binb, localStart, bucketTotal, NB);
    bscan_kernel<<<1, 256, 0, stream>>>(bucketTotal, bbase, NB);
    {
        dim3 tgrid((NB + 1 + 31) / 32, (nchunks + 31) / 32);
        transpose_ls_kernel<<<tgrid, 256, 0, stream>>>(localStart, TL, nchunks, NB + 1);
    }

    FSPack F;
    const int Arel[3] = {0, 1, 4}, Brel[3] = {2, 3, 5};
    for (int t = 0; t < 3; ++t) {
        F.c0A[t] = P.r[Arel[t]].chunk0; F.cntA[t] = relchunks[Arel[t]]; F.offA[t] = eoff_[Arel[t]];
        F.c0B[t] = P.r[Brel[t]].chunk0; F.cntB[t] = relchunks[Brel[t]]; F.offB[t] = eoff_[Brel[t]];
    }
    finesort_kernel<<<NB, 512, 0, stream>>>(
        pay, binb, TL, bbase, F, p2, arena, nbU, nbV, NU, NV, NF, NB, ntot_rows, nchunks);

    // ---- gather (+ReLU) ----
    GatherPack G;
    G.srcA[0] = (const unsigned*)utab;  G.srcB[0] = (const unsigned*)utab;  // unified
    G.srcA[1] = (const unsigned*)vtab;  G.srcB[1] = (const unsigned*)vtab;  // unified
    G.srcA[2] = (const unsigned*)u2f;   G.srcB[2] = (const unsigned*)v2f;
    G.n0 = NU; G.n1 = NU + NV;

    gather_all_kernel<<<(ntot_rows + 3) / 4, 256, 0, stream>>>(
        p2, arena, G, (float*)d_out, ntot_rows);
}

// Round 9
// 500.787 us; speedup vs baseline: 1.0473x; 1.0234x over previous
//
#include <hip/hip_runtime.h>

// ---------------------------------------------------------------------------
// HeteroTripartiteGCN, round 18: slim the sort machinery.
//   r8 budget: gather 117 (top), bucketize+finesort both just under 117,
//   directory overhead (11MB localStart + 22MB transpose) still paid.
//   Changes vs r17:
//   - bucketize pass A reads rows+cols+vals ONCE and parks the FINAL pay
//     word in registers; pass B is pure LDS (no vals re-read).
//   - localStart/TL are u16 (within-chunk offsets <= 4096): halves
//     directory write + transpose traffic; bscan fused into transpose
//     kernel (block (0,0)) -> one less launch.
//   - finesort pass1/2 use 4-lane groups (128 runs in flight, ~80% lane
//     efficiency at run lengths 5-26) instead of 16-lane (33% eff).
//   - transform + gather (pinned 4-deep pipeline) untouched.
// d_out: [msg_u | msg_v | msg_f] fp32, every row written exactly once.
// ---------------------------------------------------------------------------

#define TDIM 64
#define EPB  4096
#define STCAP 10240   // finesort LDS segment capacity (40KB)

struct Rel {
    const int* rows; const int* cols; const float* vals;
    int n, chunk0, boff, shift, srcflag, eoff, coladd;
};
struct RelPack { Rel r[6]; };

struct TPack {
    const float* X[3]; const float* W1[3]; const float* W2[3];
    unsigned short* Y1[3]; unsigned short* Y2[3];
    int N[3]; int c0[3];
};

struct FSPack {              // per output type: the two source relations
    int c0A[3], cntA[3], offA[3];
    int c0B[3], cntB[3], offB[3];
};

struct GatherPack {
    const unsigned* srcA[3]; const unsigned* srcB[3];
    int n0, n1;   // NU, NU+NV
};

__device__ __forceinline__ unsigned short f2bf(float f) {
    union { float f; unsigned u; } c; c.f = f;
    unsigned r = c.u + 0x7FFFu + ((c.u >> 16) & 1u);  // RNE
    return (unsigned short)(r >> 16);
}
__device__ __forceinline__ float bflo(unsigned x) { return __uint_as_float(x << 16); }
__device__ __forceinline__ float bfhi(unsigned x) { return __uint_as_float(x & 0xFFFF0000u); }
__device__ __forceinline__ float pval(unsigned p) {
    return __uint_as_float((p & 0x7FFFu) << 16);     // bf16 val, sign==0
}

// ---------------- fused dense transforms (fp32 in, bf16 out) ----------------
__global__ __launch_bounds__(256) void transform_fused_kernel(TPack T)
{
    __shared__ float xsT[64 * 68];
    __shared__ float w1s[64 * 64];
    __shared__ float w2s[64 * 64];

    int t = 0;
    if ((int)blockIdx.x >= T.c0[1]) t = 1;
    if ((int)blockIdx.x >= T.c0[2]) t = 2;
    const float* __restrict__ X  = T.X[t];
    const float* __restrict__ W1 = T.W1[t];
    const float* __restrict__ W2 = T.W2[t];
    unsigned short* __restrict__ Y1 = T.Y1[t];
    unsigned short* __restrict__ Y2 = T.Y2[t];
    const int N    = T.N[t];
    const int row0 = (blockIdx.x - T.c0[t]) * 64;
    const int tid  = threadIdx.x;

    for (int i = tid * 4; i < 4096; i += 256 * 4) {
        *(float4*)&w1s[i] = *(const float4*)&W1[i];
        *(float4*)&w2s[i] = *(const float4*)&W2[i];
    }
    {
        const int r  = tid >> 2;
        const int c0 = (tid & 3) * 16;
        const int gr = row0 + r;
        #pragma unroll
        for (int cc = 0; cc < 16; cc += 4) {
            const int c = c0 + cc;
            float4 v = make_float4(0.f, 0.f, 0.f, 0.f);
            if (gr < N) v = *(const float4*)&X[(size_t)gr * TDIM + c];
            xsT[(c + 0) * 68 + r] = v.x;
            xsT[(c + 1) * 68 + r] = v.y;
            xsT[(c + 2) * 68 + r] = v.z;
            xsT[(c + 3) * 68 + r] = v.w;
        }
    }
    __syncthreads();

    const int tx = tid & 15;
    const int ty = tid >> 4;
    float a1[4][4] = {{0.f}}, a2[4][4] = {{0.f}};

    #pragma unroll 8
    for (int k = 0; k < 64; ++k) {
        const float4 xv = *(const float4*)&xsT[k * 68 + ty * 4];
        const float4 w1 = *(const float4*)&w1s[k * 64 + tx * 4];
        const float4 w2 = *(const float4*)&w2s[k * 64 + tx * 4];
        const float xr[4] = {xv.x, xv.y, xv.z, xv.w};
        const float c1[4] = {w1.x, w1.y, w1.z, w1.w};
        const float c2[4] = {w2.x, w2.y, w2.z, w2.w};
        #pragma unroll
        for (int r = 0; r < 4; ++r)
            #pragma unroll
            for (int c = 0; c < 4; ++c) {
                a1[r][c] = fmaf(xr[r], c1[c], a1[r][c]);
                a2[r][c] = fmaf(xr[r], c2[c], a2[r][c]);
            }
    }
    #pragma unroll
    for (int r = 0; r < 4; ++r) {
        const int gr = row0 + ty * 4 + r;
        if (gr < N) {
            ushort4 o1, o2;
            o1.x = f2bf(a1[r][0]); o1.y = f2bf(a1[r][1]);
            o1.z = f2bf(a1[r][2]); o1.w = f2bf(a1[r][3]);
            o2.x = f2bf(a2[r][0]); o2.y = f2bf(a2[r][1]);
            o2.z = f2bf(a2[r][2]); o2.w = f2bf(a2[r][3]);
            ((ushort4*)Y1)[(size_t)gr * 16 + tx] = o1;
            ((ushort4*)Y2)[(size_t)gr * 16 + tx] = o2;
        }
    }
}

__device__ __forceinline__ int find_rel(const RelPack& P, int chunk) {
    int ri = 0;
    if (chunk >= P.r[1].chunk0) ri = 1;
    if (chunk >= P.r[2].chunk0) ri = 2;
    if (chunk >= P.r[3].chunk0) ri = 3;
    if (chunk >= P.r[4].chunk0) ri = 4;
    if (chunk >= P.r[5].chunk0) ri = 5;
    return ri;
}

// ---------------- bucketize, chunk-major, LDS-staged, one global pass ------
// Pass A: read rows/cols/vals once; park (bucket<<8|rowlocal) and the FINAL
// pay word ((colp<<15)|val15) in registers; LDS histogram.
// Scan (3 bins/thread) -> u16 localStart + cursors + bucketTotal atomics.
// Pass B: pure-LDS scatter of pay/binb into staging.
// Pass C: coalesced stream-out (binb dword-packed, guarded tail).
__global__ __launch_bounds__(512) void bucketize_cm_kernel(
    RelPack P, unsigned* __restrict__ pay, unsigned char* __restrict__ binb,
    unsigned short* __restrict__ localStart, int* __restrict__ bucketTotal,
    int NB)
{
    __shared__ int cnt[1536];
    __shared__ int sh[512];
    __shared__ unsigned stage_pay[EPB];        // 16 KB
    __shared__ unsigned char stage_bin[EPB];   // 4 KB

    const int tid   = threadIdx.x;
    const int chunk = blockIdx.x;
    for (int t = tid; t < NB; t += 512) cnt[t] = 0;
    __syncthreads();

    const int ri = find_rel(P, chunk);
    const Rel M = P.r[ri];
    const int i0    = (chunk - M.chunk0) * EPB;
    const int rbase = M.eoff + i0;          // chunk's record segment base
    const int count = min(EPB, M.n - i0);   // valid records in this chunk

    const int mask = (1 << M.shift) - 1;
    const unsigned sf = (unsigned)M.srcflag;

    // pass A: histogram + park final payload in registers
    int      m_[EPB / 512];                 // (bucket<<8) | rowlocal, -1 invalid
    unsigned x_[EPB / 512];                 // final pay word
    #pragma unroll
    for (int k = 0; k < EPB / 512; ++k) {
        const int i = i0 + tid + k * 512;
        m_[k] = -1;
        if (i < M.n) {
            const int row = M.rows[i];
            const int b   = M.boff + (row >> M.shift);
            m_[k] = (b << 8) | (row & mask);
            const unsigned colp = (unsigned)M.cols[i] + (unsigned)M.coladd;
            x_[k] = (colp << 15) | ((unsigned)f2bf(M.vals[i]) & 0x7FFFu);
            atomicAdd(&cnt[b], 1);
        }
    }
    __syncthreads();

    // bucket totals + LDS exclusive scan, 3 bins/thread (NB <= 1536)
    int myv[3]; int lsum = 0;
    #pragma unroll
    for (int j = 0; j < 3; ++j) {
        const int idx = tid * 3 + j;
        myv[j] = (idx < NB) ? cnt[idx] : 0;
        lsum += myv[j];
    }
    sh[tid] = lsum;
    __syncthreads();
    for (int off = 1; off < 512; off <<= 1) {
        const int x = (tid >= off) ? sh[tid - off] : 0;
        __syncthreads();
        sh[tid] += x;
        __syncthreads();
    }
    int prefix = tid ? sh[tid - 1] : 0;
    const size_t lb = (size_t)chunk * (NB + 1);
    #pragma unroll
    for (int j = 0; j < 3; ++j) {
        const int idx = tid * 3 + j;
        if (idx < NB) {
            localStart[lb + idx] = (unsigned short)prefix;
            if (myv[j]) atomicAdd(&bucketTotal[idx], myv[j]);
            cnt[idx] = prefix;              // cursor
        } else if (idx == NB) {
            localStart[lb + NB] = (unsigned short)prefix;
        }
        prefix += myv[j];
    }
    __syncthreads();

    // pass B: pure-LDS scatter into staging
    #pragma unroll
    for (int k = 0; k < EPB / 512; ++k) {
        if (m_[k] >= 0) {
            const int b   = m_[k] >> 8;
            const int pos = atomicAdd(&cnt[b], 1);
            stage_pay[pos] = x_[k];
            stage_bin[pos] = (unsigned char)(((m_[k] & 255) << 1) | sf);
        }
    }
    __syncthreads();

    // pass C: coalesced stream-out
    #pragma unroll
    for (int k = 0; k < EPB / 512; ++k) {
        const int j = tid + k * 512;
        if (j < count) pay[rbase + j] = stage_pay[j];
    }
    // binb: dword-packed; guarded tail (rel boundaries aren't 4-aligned)
    {
        const int nfull = count >> 2;
        unsigned* bout = (unsigned*)(binb + rbase);      // rbase % 4 == 0
        const unsigned* bsrc = (const unsigned*)stage_bin;
        for (int j = tid; j < nfull; j += 512) bout[j] = bsrc[j];
        if (tid < (count & 3)) binb[rbase + nfull * 4 + tid] = stage_bin[nfull * 4 + tid];
    }
}

// ---------------- bscan (block 0,0) + u16 directory transpose --------------
__global__ __launch_bounds__(256) void bscan_transpose_kernel(
    const int* __restrict__ bucketTotal, int* __restrict__ bbase, int NB,
    const unsigned short* __restrict__ src, unsigned short* __restrict__ dst,
    int rows, int cols)
{
    __shared__ int shb[256];
    __shared__ int carry;
    __shared__ unsigned short tile[32][33];

    const int t = threadIdx.x;

    if (blockIdx.x == 0 && blockIdx.y == 0) {
        // exclusive scan of bucketTotal -> bbase
        if (t == 0) carry = 0;
        __syncthreads();
        for (int b0 = 0; b0 < NB; b0 += 256) {
            const int idx = b0 + t;
            const int c = (idx < NB) ? bucketTotal[idx] : 0;
            shb[t] = c;
            __syncthreads();
            for (int off = 1; off < 256; off <<= 1) {
                const int x = (t >= off) ? shb[t - off] : 0;
                __syncthreads();
                shb[t] += x;
                __syncthreads();
            }
            const int cbase = carry;
            if (idx < NB) bbase[idx] = cbase + shb[t] - c;
            __syncthreads();
            if (t == 0) carry = cbase + shb[255];
            __syncthreads();
        }
        if (t == 0) bbase[NB] = carry;
        __syncthreads();
    }

    // tile transpose: src[r][c] (stride cols) -> dst[c][r] (stride rows)
    const int c0 = blockIdx.x * 32;
    const int r0 = blockIdx.y * 32;
    const int tx = t & 31;
    const int ty = t >> 5;     // 0..7
    #pragma unroll
    for (int k = 0; k < 32; k += 8) {
        const int r = r0 + ty + k, c = c0 + tx;
        if (r < rows && c < cols) tile[ty + k][tx] = src[(size_t)r * cols + c];
    }
    __syncthreads();
    #pragma unroll
    for (int k = 0; k < 32; k += 8) {
        const int c = c0 + ty + k, r = r0 + tx;
        if (c < cols && r < rows) dst[(size_t)c * rows + r] = tile[tx][ty + k];
    }
}

// ---------------- finesort: block per bucket, LDS-staged arena segment ----
// 4-lane groups (128 runs in flight): run lengths are 5-26 edges, so 16-lane
// groups idled ~2/3 of lanes; 4-lane keeps efficiency high and quadruples
// the number of concurrent latency chains.
__global__ __launch_bounds__(512) void finesort_kernel(
    const unsigned* __restrict__ pay, const unsigned char* __restrict__ binb,
    const unsigned short* __restrict__ TL, const int* __restrict__ bbase,
    FSPack F, int* __restrict__ p2, unsigned* __restrict__ arena,
    int nbU, int nbV, int NU, int NV, int NF, int NB, int ntot_rows,
    int nchunksTot)
{
    __shared__ int cnt[512];
    __shared__ int sh[512];
    __shared__ int runS[1024], runE[1024];
    __shared__ unsigned stage[STCAP];    // 40 KB

    const int b   = blockIdx.x;
    const int tid = threadIdx.x;

    int t, lb, rowbase;
    if (b < nbU)              { t = 0; lb = b;              rowbase = 0; }
    else if (b < nbU + nbV)   { t = 1; lb = b - nbU;        rowbase = NU; }
    else                      { t = 2; lb = b - nbU - nbV;  rowbase = NU + NV; }
    const int shift     = (t == 2) ? 5 : 7;
    const int Ntype     = (t == 0) ? NU : (t == 1) ? NV : NF;
    const int row_start = lb << shift;
    const int nrows     = min(1 << shift, Ntype - row_start);
    const int nbins     = (1 << shift) * 2;
    const int grow0     = rowbase + row_start;

    const int nA = F.cntA[t], nB_ = F.cntB[t];
    const int nRuns = nA + nB_;

    // run directory: TL[b][chunk] and TL[b+1][chunk] are contiguous u16 rows
    const unsigned short* __restrict__ TLb  = TL + (size_t)b * nchunksTot;
    const unsigned short* __restrict__ TLb1 = TL + (size_t)(b + 1) * nchunksTot;
    for (int i = tid; i < nRuns; i += 512) {
        int ci, base;
        if (i < nA) { ci = F.c0A[t] + i;        base = F.offA[t] + i * EPB; }
        else        { int k = i - nA;
                      ci = F.c0B[t] + k;        base = F.offB[t] + k * EPB; }
        runS[i] = base + (int)TLb[ci];
        runE[i] = base + (int)TLb1[ci];
    }
    if (tid < nbins) cnt[tid] = 0;
    __syncthreads();

    const int s = bbase[b];
    const int e = bbase[b + 1];
    const bool staged = (e - s) <= STCAP;
    const int grp = tid >> 2;        // 128 groups of 4 lanes
    const int gl  = tid & 3;

    // pass 1: count fine bins (1B/edge)
    for (int ridx = grp; ridx < nRuns; ridx += 128) {
        const int rs = runS[ridx], re = runE[ridx];
        for (int j = rs + gl; j < re; j += 4) {
            atomicAdd(&cnt[binb[j]], 1);
        }
    }
    __syncthreads();

    // exclusive scan over nbins (<=256)
    const int v = (tid < nbins) ? cnt[tid] : 0;
    sh[tid] = v;
    __syncthreads();
    for (int off = 1; off < 512; off <<= 1) {
        const int x = (tid >= off) ? sh[tid - off] : 0;
        __syncthreads();
        sh[tid] += x;
        __syncthreads();
    }
    const int excl = sh[tid] - v;
    if (tid < nbins) cnt[tid] = staged ? excl : (s + excl);   // cursors
    if (tid < nrows * 2) p2[2 * grow0 + tid] = s + excl;
    if (b == NB - 1 && tid == 0) p2[2 * ntot_rows] = e;
    __syncthreads();

    if (staged) {
        // pass 2: scatter payload into LDS segment (relative positions)
        for (int ridx = grp; ridx < nRuns; ridx += 128) {
            const int rs = runS[ridx], re = runE[ridx];
            for (int j = rs + gl; j < re; j += 4) {
                const int pos = atomicAdd(&cnt[binb[j]], 1);
                stage[pos] = pay[j];
            }
        }
        __syncthreads();
        // pass 3: coalesced stream-out of the bucket segment
        const int seglen = e - s;
        for (int j = tid; j < seglen; j += 512) arena[s + j] = stage[j];
    } else {
        // fallback (not expected at these sizes): direct global scatter
        for (int ridx = grp; ridx < nRuns; ridx += 128) {
            const int rs = runS[ridx], re = runE[ridx];
            for (int j = rs + gl; j < re; j += 4) {
                const int pos = atomicAdd(&cnt[binb[j]], 1);
                arena[pos] = pay[j];
            }
        }
    }
}

// ---------------- gather: wave/row, 8 lanes/edge, pinned 4-deep pipeline ---
__device__ __forceinline__ void accum_seg(
    const unsigned* __restrict__ src, const unsigned* __restrict__ arena,
    const int s, const int e, const int g, const int li4,
    float (&acc)[8])
{
    if (s >= e) return;
    const int nb = (e - s + 7) >> 3;
    const unsigned* __restrict__ srcp = src + li4;   // hoist lane offset

    unsigned x0[4], x1[4], x2[4], x3[4];
    float w0, w1, w2, w3;

    auto issue = [&](int j, unsigned* x, float& w) {
        const int idx = j + g;
        const bool ok = idx < e;
        const unsigned cv = arena[ok ? idx : s];      // clamped: always valid
        w = ok ? pval(cv) : 0.f;
        const uint4 xv = *(const uint4*)&srcp[(cv >> 15) * 32u];
        x[0] = xv.x; x[1] = xv.y; x[2] = xv.z; x[3] = xv.w;
    };
    auto fmab = [&](const unsigned* x, float w) {
        #pragma unroll
        for (int q = 0; q < 4; ++q) {
            acc[2 * q]     = fmaf(w, bflo(x[q]), acc[2 * q]);
            acc[2 * q + 1] = fmaf(w, bfhi(x[q]), acc[2 * q + 1]);
        }
    };

    issue(s,      x0, w0);
    issue(s + 8,  x1, w1);
    issue(s + 16, x2, w2);
    issue(s + 24, x3, w3);
    __builtin_amdgcn_sched_barrier(0);

    int k = 0;
    for (;;) {
        fmab(x0, w0);
        if (k + 4 < nb) issue(s + (k + 4) * 8, x0, w0);
        __builtin_amdgcn_sched_barrier(0);
        if (++k >= nb) break;
        fmab(x1, w1);
        if (k + 4 < nb) issue(s + (k + 4) * 8, x1, w1);
        __builtin_amdgcn_sched_barrier(0);
        if (++k >= nb) break;
        fmab(x2, w2);
        if (k + 4 < nb) issue(s + (k + 4) * 8, x2, w2);
        __builtin_amdgcn_sched_barrier(0);
        if (++k >= nb) break;
        fmab(x3, w3);
        if (k + 4 < nb) issue(s + (k + 4) * 8, x3, w3);
        __builtin_amdgcn_sched_barrier(0);
        if (++k >= nb) break;
    }
}

__global__ __launch_bounds__(256) void gather_all_kernel(
    const int* __restrict__ p2, const unsigned* __restrict__ arena,
    GatherPack G, float* __restrict__ out, int nrow_total)
{
    const int gid  = (blockIdx.x * 256 + threadIdx.x) >> 6;
    const int lane = threadIdx.x & 63;
    const int g    = lane >> 3;          // edge slot within block
    const int li   = lane & 7;           // component slice
    const int li4  = li * 4;             // u32 offset within row
    if (gid >= nrow_total) return;
    const int wid = nrow_total - 1 - gid;   // long f-rows first

    int seg = 0;
    if (wid >= G.n1)      seg = 2;
    else if (wid >= G.n0) seg = 1;
    seg = __builtin_amdgcn_readfirstlane(seg);

    const int pa = __builtin_amdgcn_readfirstlane(p2[2 * wid]);
    const int pe = __builtin_amdgcn_readfirstlane(p2[2 * wid + 2]);

    float acc[8];
    #pragma unroll
    for (int k = 0; k < 8; ++k) acc[k] = 0.f;

    if (seg < 2) {
        accum_seg(G.srcA[seg], arena, pa, pe, g, li4, acc);
    } else {
        const int pm = __builtin_amdgcn_readfirstlane(p2[2 * wid + 1]);
        accum_seg(G.srcA[2], arena, pa, pm, g, li4, acc);
        accum_seg(G.srcB[2], arena, pm, pe, g, li4, acc);
    }

    #pragma unroll
    for (int k = 0; k < 8; ++k) {
        acc[k] += __shfl_xor(acc[k], 8, 64);
        acc[k] += __shfl_xor(acc[k], 16, 64);
        acc[k] += __shfl_xor(acc[k], 32, 64);
    }

    if (g == 0) {
        float4 o0, o1;
        o0.x = fmaxf(acc[0], 0.f); o0.y = fmaxf(acc[1], 0.f);
        o0.z = fmaxf(acc[2], 0.f); o0.w = fmaxf(acc[3], 0.f);
        o1.x = fmaxf(acc[4], 0.f); o1.y = fmaxf(acc[5], 0.f);
        o1.z = fmaxf(acc[6], 0.f); o1.w = fmaxf(acc[7], 0.f);
        float4* dst = (float4*)(out + (size_t)wid * 64 + li * 8);
        dst[0] = o0;
        dst[1] = o1;
    }
}

// ---------------------------------------------------------------------------
extern "C" void kernel_launch(void* const* d_in, const int* in_sizes, int n_in,
                              void* d_out, int out_size, void* d_ws, size_t ws_size,
                              hipStream_t stream)
{
    const float* x_u    = (const float*)d_in[0];
    const float* x_v    = (const float*)d_in[1];
    const float* x_f    = (const float*)d_in[2];
    const float* W_u_uv = (const float*)d_in[3];
    const float* W_v_uv = (const float*)d_in[4];
    const float* W_f2u  = (const float*)d_in[5];
    const float* W_f2v  = (const float*)d_in[6];
    const float* W_u2f  = (const float*)d_in[7];
    const float* W_v2f  = (const float*)d_in[8];

    const int* rows_[6] = {(const int*)d_in[9],  (const int*)d_in[12],
                           (const int*)d_in[15], (const int*)d_in[18],
                           (const int*)d_in[21], (const int*)d_in[24]};
    const int* cols_[6] = {(const int*)d_in[10], (const int*)d_in[13],
                           (const int*)d_in[16], (const int*)d_in[19],
                           (const int*)d_in[22], (const int*)d_in[25]};
    const float* vals_[6] = {(const float*)d_in[11], (const float*)d_in[14],
                             (const float*)d_in[17], (const float*)d_in[20],
                             (const float*)d_in[23], (const float*)d_in[26]};

    const int NU = in_sizes[0] / TDIM;
    const int NV = in_sizes[1] / TDIM;
    const int NF = in_sizes[2] / TDIM;
    const int E_[6] = {in_sizes[9], in_sizes[12], in_sizes[15],
                       in_sizes[18], in_sizes[21], in_sizes[24]};

    const int nbU = (NU + 127) >> 7;
    const int nbV = (NV + 127) >> 7;
    const int nbF = (NF + 31) >> 5;
    const int NB  = nbU + nbV + nbF;
    const int ntot_rows = NU + NV + NF;

    // u: rel0 uv (A=tmp_v), rel2 uf (B=f2u -> colp += NV)
    // v: rel1 vu (A=tmp_u), rel3 vf (B=f2v -> colp += NU)
    // f: rel4 fu (A=u2f),  rel5 fv (B=v2f)
    const int boff_[6]   = {0, nbU, 0, nbU, nbU + nbV, nbU + nbV};
    const int shift_[6]  = {7, 7, 7, 7, 5, 5};
    const int sflag_[6]  = {0, 0, 1, 1, 0, 1};
    const int coladd_[6] = {0, 0, NV, NU, 0, 0};

    size_t etot = 0;
    int eoff_[6];
    for (int r = 0; r < 6; ++r) { eoff_[r] = (int)etot; etot += (size_t)E_[r]; }

    // ---- relation pack / chunk map ----
    RelPack P;
    int nchunks = 0;
    int relchunks[6];
    for (int r = 0; r < 6; ++r) {
        P.r[r].rows = rows_[r]; P.r[r].cols = cols_[r]; P.r[r].vals = vals_[r];
        P.r[r].n = E_[r]; P.r[r].chunk0 = nchunks;
        P.r[r].boff = boff_[r]; P.r[r].shift = shift_[r]; P.r[r].srcflag = sflag_[r];
        P.r[r].eoff = eoff_[r]; P.r[r].coladd = coladd_[r];
        relchunks[r] = (E_[r] + EPB - 1) / EPB;
        nchunks += relchunks[r];
    }

    // ---- workspace ----
    char* wsb = (char*)d_ws;
    size_t o = 0;
    auto alloc = [&](size_t bytes) {
        char* p = wsb + o;
        o = (o + bytes + 15) & ~(size_t)15;
        return p;
    };
    // unified tables: [tmp_v | f2u] for u-gather, [tmp_u | f2v] for v-gather
    unsigned short* utab = (unsigned short*)alloc(((size_t)NV + NF) * TDIM * 2);
    unsigned short* vtab = (unsigned short*)alloc(((size_t)NU + NF) * TDIM * 2);
    unsigned short* u2f  = (unsigned short*)alloc((size_t)NU * TDIM * 2);
    unsigned short* v2f  = (unsigned short*)alloc((size_t)NV * TDIM * 2);
    unsigned short* tmp_v = utab;
    unsigned short* f2u   = utab + (size_t)NV * TDIM;
    unsigned short* tmp_u = vtab;
    unsigned short* f2v   = vtab + (size_t)NU * TDIM;
    unsigned short* localStart16 = (unsigned short*)alloc((size_t)nchunks * (NB + 1) * 2);
    unsigned short* TL16         = (unsigned short*)alloc((size_t)(NB + 1) * nchunks * 2);
    int* bucketTotal = (int*)alloc((size_t)NB * 4);
    int* bbase       = (int*)alloc((size_t)(NB + 1) * 4);
    int* p2          = (int*)alloc((size_t)(2 * ntot_rows + 1) * 4);
    unsigned* pay        = (unsigned*)alloc(etot * 4);
    unsigned char* binb  = (unsigned char*)alloc(etot);
    unsigned* arena      = (unsigned*)alloc(etot * 4);
    (void)ws_size;

    // ---- fused transforms ----
    TPack T;
    T.X[0] = x_u; T.W1[0] = W_u_uv; T.W2[0] = W_u2f; T.Y1[0] = tmp_u; T.Y2[0] = u2f; T.N[0] = NU;
    T.X[1] = x_v; T.W1[1] = W_v_uv; T.W2[1] = W_v2f; T.Y1[1] = tmp_v; T.Y2[1] = v2f; T.N[1] = NV;
    T.X[2] = x_f; T.W1[2] = W_f2u;  T.W2[2] = W_f2v; T.Y1[2] = f2u;  T.Y2[2] = f2v; T.N[2] = NF;
    T.c0[0] = 0;
    T.c0[1] = (NU + 63) / 64;
    T.c0[2] = T.c0[1] + (NV + 63) / 64;
    const int tchunks = T.c0[2] + (NF + 63) / 64;
    transform_fused_kernel<<<tchunks, 256, 0, stream>>>(T);

    // ---- sort pipeline ----
    hipMemsetAsync(bucketTotal, 0, (size_t)NB * sizeof(int), stream);
    bucketize_cm_kernel<<<nchunks, 512, 0, stream>>>(P, pay, binb, localStart16, bucketTotal, NB);
    {
        dim3 tgrid((NB + 1 + 31) / 32, (nchunks + 31) / 32);
        bscan_transpose_kernel<<<tgrid, 256, 0, stream>>>(
            bucketTotal, bbase, NB, localStart16, TL16, nchunks, NB + 1);
    }

    FSPack F;
    const int Arel[3] = {0, 1, 4}, Brel[3] = {2, 3, 5};
    for (int t = 0; t < 3; ++t) {
        F.c0A[t] = P.r[Arel[t]].chunk0; F.cntA[t] = relchunks[Arel[t]]; F.offA[t] = eoff_[Arel[t]];
        F.c0B[t] = P.r[Brel[t]].chunk0; F.cntB[t] = relchunks[Brel[t]]; F.offB[t] = eoff_[Brel[t]];
    }
    finesort_kernel<<<NB, 512, 0, stream>>>(
        pay, binb, TL16, bbase, F, p2, arena, nbU, nbV, NU, NV, NF, NB, ntot_rows, nchunks);

    // ---- gather (+ReLU) ----
    GatherPack G;
    G.srcA[0] = (const unsigned*)utab;  G.srcB[0] = (const unsigned*)utab;  // unified
    G.srcA[1] = (const unsigned*)vtab;  G.srcB[1] = (const unsigned*)vtab;  // unified
    G.srcA[2] = (const unsigned*)u2f;   G.srcB[2] = (const unsigned*)v2f;
    G.n0 = NU; G.n1 = NU + NV;

    gather_all_kernel<<<(ntot_rows + 3) / 4, 256, 0, stream>>>(
        p2, arena, G, (float*)d_out, ntot_rows);
}

// Round 10
// 428.371 us; speedup vs baseline: 1.2244x; 1.1690x over previous
//
#include <hip/hip_runtime.h>

// ---------------------------------------------------------------------------
// HeteroTripartiteGCN, round 19: fuse finesort + gather (kill arena+p2).
//   r9 budget: gather 119.5 + ~380us of sub-threshold kernels. finesort's
//   sorted bucket payload already sits in LDS before being written to HBM
//   (34MB) and read back by gather (34MB). Fusing gather into the finesort
//   block removes: arena W+R, p2 W+R, bucketTotal+bbase+bscan, one launch.
//   Fused block: run-dir load -> binb count -> scan (rowptr in LDS) ->
//   pay scatter into LDS stage -> 8 waves gather rows off LDS with the
//   proven 8-lane/edge 4-deep pinned pipeline -> out(+ReLU).
//   Overflow (>STCAP, >=6.5 sigma) -> global scratch via atomic cursor.
//   Block order reversed so the largest (f) buckets launch first.
//   bucketize loses bucketTotal atomics; transpose is now pure u16.
// d_out: [msg_u | msg_v | msg_f] fp32, every row written exactly once.
// ---------------------------------------------------------------------------

#define TDIM 64
#define EPB  4096
#define STCAP 10240   // fused LDS segment capacity (40KB)

struct Rel {
    const int* rows; const int* cols; const float* vals;
    int n, chunk0, boff, shift, srcflag, eoff, coladd;
};
struct RelPack { Rel r[6]; };

struct TPack {
    const float* X[3]; const float* W1[3]; const float* W2[3];
    unsigned short* Y1[3]; unsigned short* Y2[3];
    int N[3]; int c0[3];
};

struct FSPack {              // per output type: the two source relations
    int c0A[3], cntA[3], offA[3];
    int c0B[3], cntB[3], offB[3];
};

__device__ __forceinline__ unsigned short f2bf(float f) {
    union { float f; unsigned u; } c; c.f = f;
    unsigned r = c.u + 0x7FFFu + ((c.u >> 16) & 1u);  // RNE
    return (unsigned short)(r >> 16);
}
__device__ __forceinline__ float bflo(unsigned x) { return __uint_as_float(x << 16); }
__device__ __forceinline__ float bfhi(unsigned x) { return __uint_as_float(x & 0xFFFF0000u); }
__device__ __forceinline__ float pval(unsigned p) {
    return __uint_as_float((p & 0x7FFFu) << 16);     // bf16 val, sign==0
}

// ---------------- fused dense transforms (fp32 in, bf16 out) ----------------
__global__ __launch_bounds__(256) void transform_fused_kernel(TPack T)
{
    __shared__ float xsT[64 * 68];
    __shared__ float w1s[64 * 64];
    __shared__ float w2s[64 * 64];

    int t = 0;
    if ((int)blockIdx.x >= T.c0[1]) t = 1;
    if ((int)blockIdx.x >= T.c0[2]) t = 2;
    const float* __restrict__ X  = T.X[t];
    const float* __restrict__ W1 = T.W1[t];
    const float* __restrict__ W2 = T.W2[t];
    unsigned short* __restrict__ Y1 = T.Y1[t];
    unsigned short* __restrict__ Y2 = T.Y2[t];
    const int N    = T.N[t];
    const int row0 = (blockIdx.x - T.c0[t]) * 64;
    const int tid  = threadIdx.x;

    for (int i = tid * 4; i < 4096; i += 256 * 4) {
        *(float4*)&w1s[i] = *(const float4*)&W1[i];
        *(float4*)&w2s[i] = *(const float4*)&W2[i];
    }
    {
        const int r  = tid >> 2;
        const int c0 = (tid & 3) * 16;
        const int gr = row0 + r;
        #pragma unroll
        for (int cc = 0; cc < 16; cc += 4) {
            const int c = c0 + cc;
            float4 v = make_float4(0.f, 0.f, 0.f, 0.f);
            if (gr < N) v = *(const float4*)&X[(size_t)gr * TDIM + c];
            xsT[(c + 0) * 68 + r] = v.x;
            xsT[(c + 1) * 68 + r] = v.y;
            xsT[(c + 2) * 68 + r] = v.z;
            xsT[(c + 3) * 68 + r] = v.w;
        }
    }
    __syncthreads();

    const int tx = tid & 15;
    const int ty = tid >> 4;
    float a1[4][4] = {{0.f}}, a2[4][4] = {{0.f}};

    #pragma unroll 8
    for (int k = 0; k < 64; ++k) {
        const float4 xv = *(const float4*)&xsT[k * 68 + ty * 4];
        const float4 w1 = *(const float4*)&w1s[k * 64 + tx * 4];
        const float4 w2 = *(const float4*)&w2s[k * 64 + tx * 4];
        const float xr[4] = {xv.x, xv.y, xv.z, xv.w};
        const float c1[4] = {w1.x, w1.y, w1.z, w1.w};
        const float c2[4] = {w2.x, w2.y, w2.z, w2.w};
        #pragma unroll
        for (int r = 0; r < 4; ++r)
            #pragma unroll
            for (int c = 0; c < 4; ++c) {
                a1[r][c] = fmaf(xr[r], c1[c], a1[r][c]);
                a2[r][c] = fmaf(xr[r], c2[c], a2[r][c]);
            }
    }
    #pragma unroll
    for (int r = 0; r < 4; ++r) {
        const int gr = row0 + ty * 4 + r;
        if (gr < N) {
            ushort4 o1, o2;
            o1.x = f2bf(a1[r][0]); o1.y = f2bf(a1[r][1]);
            o1.z = f2bf(a1[r][2]); o1.w = f2bf(a1[r][3]);
            o2.x = f2bf(a2[r][0]); o2.y = f2bf(a2[r][1]);
            o2.z = f2bf(a2[r][2]); o2.w = f2bf(a2[r][3]);
            ((ushort4*)Y1)[(size_t)gr * 16 + tx] = o1;
            ((ushort4*)Y2)[(size_t)gr * 16 + tx] = o2;
        }
    }
}

__device__ __forceinline__ int find_rel(const RelPack& P, int chunk) {
    int ri = 0;
    if (chunk >= P.r[1].chunk0) ri = 1;
    if (chunk >= P.r[2].chunk0) ri = 2;
    if (chunk >= P.r[3].chunk0) ri = 3;
    if (chunk >= P.r[4].chunk0) ri = 4;
    if (chunk >= P.r[5].chunk0) ri = 5;
    return ri;
}

// ---------------- bucketize, chunk-major, LDS-staged, one global pass ------
__global__ __launch_bounds__(512) void bucketize_cm_kernel(
    RelPack P, unsigned* __restrict__ pay, unsigned char* __restrict__ binb,
    unsigned short* __restrict__ localStart, int NB)
{
    __shared__ int cnt[1536];
    __shared__ int sh[512];
    __shared__ unsigned stage_pay[EPB];        // 16 KB
    __shared__ unsigned char stage_bin[EPB];   // 4 KB

    const int tid   = threadIdx.x;
    const int chunk = blockIdx.x;
    for (int t = tid; t < NB; t += 512) cnt[t] = 0;
    __syncthreads();

    const int ri = find_rel(P, chunk);
    const Rel M = P.r[ri];
    const int i0    = (chunk - M.chunk0) * EPB;
    const int rbase = M.eoff + i0;          // chunk's record segment base
    const int count = min(EPB, M.n - i0);   // valid records in this chunk

    const int mask = (1 << M.shift) - 1;
    const unsigned sf = (unsigned)M.srcflag;

    // pass A: histogram + park final payload in registers
    int      m_[EPB / 512];                 // (bucket<<8) | rowlocal, -1 invalid
    unsigned x_[EPB / 512];                 // final pay word
    #pragma unroll
    for (int k = 0; k < EPB / 512; ++k) {
        const int i = i0 + tid + k * 512;
        m_[k] = -1;
        if (i < M.n) {
            const int row = M.rows[i];
            const int b   = M.boff + (row >> M.shift);
            m_[k] = (b << 8) | (row & mask);
            const unsigned colp = (unsigned)M.cols[i] + (unsigned)M.coladd;
            x_[k] = (colp << 15) | ((unsigned)f2bf(M.vals[i]) & 0x7FFFu);
            atomicAdd(&cnt[b], 1);
        }
    }
    __syncthreads();

    // LDS exclusive scan, 3 bins/thread (NB <= 1536)
    int myv[3]; int lsum = 0;
    #pragma unroll
    for (int j = 0; j < 3; ++j) {
        const int idx = tid * 3 + j;
        myv[j] = (idx < NB) ? cnt[idx] : 0;
        lsum += myv[j];
    }
    sh[tid] = lsum;
    __syncthreads();
    for (int off = 1; off < 512; off <<= 1) {
        const int x = (tid >= off) ? sh[tid - off] : 0;
        __syncthreads();
        sh[tid] += x;
        __syncthreads();
    }
    int prefix = tid ? sh[tid - 1] : 0;
    const size_t lb = (size_t)chunk * (NB + 1);
    #pragma unroll
    for (int j = 0; j < 3; ++j) {
        const int idx = tid * 3 + j;
        if (idx < NB) {
            localStart[lb + idx] = (unsigned short)prefix;
            cnt[idx] = prefix;              // cursor
        } else if (idx == NB) {
            localStart[lb + NB] = (unsigned short)prefix;
        }
        prefix += myv[j];
    }
    __syncthreads();

    // pass B: pure-LDS scatter into staging
    #pragma unroll
    for (int k = 0; k < EPB / 512; ++k) {
        if (m_[k] >= 0) {
            const int b   = m_[k] >> 8;
            const int pos = atomicAdd(&cnt[b], 1);
            stage_pay[pos] = x_[k];
            stage_bin[pos] = (unsigned char)(((m_[k] & 255) << 1) | sf);
        }
    }
    __syncthreads();

    // pass C: coalesced stream-out
    #pragma unroll
    for (int k = 0; k < EPB / 512; ++k) {
        const int j = tid + k * 512;
        if (j < count) pay[rbase + j] = stage_pay[j];
    }
    // binb: dword-packed; guarded tail (rel boundaries aren't 4-aligned)
    {
        const int nfull = count >> 2;
        unsigned* bout = (unsigned*)(binb + rbase);      // rbase % 4 == 0
        const unsigned* bsrc = (const unsigned*)stage_bin;
        for (int j = tid; j < nfull; j += 512) bout[j] = bsrc[j];
        if (tid < (count & 3)) binb[rbase + nfull * 4 + tid] = stage_bin[nfull * 4 + tid];
    }
}

// ---------------- u16 directory transpose ----------------
__global__ __launch_bounds__(256) void transpose16_kernel(
    const unsigned short* __restrict__ src, unsigned short* __restrict__ dst,
    int rows, int cols)
{   // src[r][c] (stride cols) -> dst[c][r] (stride rows)
    __shared__ unsigned short tile[32][33];
    const int c0 = blockIdx.x * 32;
    const int r0 = blockIdx.y * 32;
    const int tx = threadIdx.x & 31;
    const int ty = threadIdx.x >> 5;     // 0..7
    #pragma unroll
    for (int k = 0; k < 32; k += 8) {
        const int r = r0 + ty + k, c = c0 + tx;
        if (r < rows && c < cols) tile[ty + k][tx] = src[(size_t)r * cols + c];
    }
    __syncthreads();
    #pragma unroll
    for (int k = 0; k < 32; k += 8) {
        const int c = c0 + ty + k, r = r0 + tx;
        if (c < cols && r < rows) dst[(size_t)c * rows + r] = tile[tx][ty + k];
    }
}

// ---------------- fused finesort+gather ----------------
// 8-lane/edge accumulate over seg[s..e) (LDS stage via flat, or global FB).
__device__ __forceinline__ void accum_seg(
    const unsigned* __restrict__ src, const unsigned* seg,
    const int s, const int e, const int g, const int li4,
    float (&acc)[8])
{
    if (s >= e) return;
    const int nb = (e - s + 7) >> 3;
    const unsigned* __restrict__ srcp = src + li4;   // hoist lane offset

    unsigned x0[4], x1[4], x2[4], x3[4];
    float w0, w1, w2, w3;

    auto issue = [&](int j, unsigned* x, float& w) {
        const int idx = j + g;
        const bool ok = idx < e;
        const unsigned cv = seg[ok ? idx : s];        // clamped: always valid
        w = ok ? pval(cv) : 0.f;
        const uint4 xv = *(const uint4*)&srcp[(cv >> 15) * 32u];
        x[0] = xv.x; x[1] = xv.y; x[2] = xv.z; x[3] = xv.w;
    };
    auto fmab = [&](const unsigned* x, float w) {
        #pragma unroll
        for (int q = 0; q < 4; ++q) {
            acc[2 * q]     = fmaf(w, bflo(x[q]), acc[2 * q]);
            acc[2 * q + 1] = fmaf(w, bfhi(x[q]), acc[2 * q + 1]);
        }
    };

    issue(s,      x0, w0);
    issue(s + 8,  x1, w1);
    issue(s + 16, x2, w2);
    issue(s + 24, x3, w3);
    __builtin_amdgcn_sched_barrier(0);

    int k = 0;
    for (;;) {
        fmab(x0, w0);
        if (k + 4 < nb) issue(s + (k + 4) * 8, x0, w0);
        __builtin_amdgcn_sched_barrier(0);
        if (++k >= nb) break;
        fmab(x1, w1);
        if (k + 4 < nb) issue(s + (k + 4) * 8, x1, w1);
        __builtin_amdgcn_sched_barrier(0);
        if (++k >= nb) break;
        fmab(x2, w2);
        if (k + 4 < nb) issue(s + (k + 4) * 8, x2, w2);
        __builtin_amdgcn_sched_barrier(0);
        if (++k >= nb) break;
        fmab(x3, w3);
        if (k + 4 < nb) issue(s + (k + 4) * 8, x3, w3);
        __builtin_amdgcn_sched_barrier(0);
        if (++k >= nb) break;
    }
}

__global__ __launch_bounds__(512) void finesort_gather_kernel(
    const unsigned* __restrict__ pay, const unsigned char* __restrict__ binb,
    const unsigned short* __restrict__ TL, FSPack F,
    const unsigned* __restrict__ srcU, const unsigned* __restrict__ srcV,
    const unsigned* __restrict__ srcFA, const unsigned* __restrict__ srcFB,
    unsigned* __restrict__ fbuf, int* __restrict__ fbCursor,
    float* __restrict__ out,
    int nbU, int nbV, int NU, int NV, int NF, int NB, int nchunksTot)
{
    __shared__ int cnt[256];
    __shared__ int sh[512];
    __shared__ int rowptr[257];
    __shared__ int runS[1024];
    __shared__ unsigned short runL[1024];
    __shared__ unsigned stage[STCAP];    // 40 KB
    __shared__ int fbOff;

    const int b   = NB - 1 - (int)blockIdx.x;   // largest (f) buckets first
    const int tid = threadIdx.x;

    int t, lb, rowbase;
    if (b < nbU)              { t = 0; lb = b;              rowbase = 0; }
    else if (b < nbU + nbV)   { t = 1; lb = b - nbU;        rowbase = NU; }
    else                      { t = 2; lb = b - nbU - nbV;  rowbase = NU + NV; }
    const int shift     = (t == 2) ? 5 : 7;
    const int Ntype     = (t == 0) ? NU : (t == 1) ? NV : NF;
    const int row_start = lb << shift;
    const int nrows     = min(1 << shift, Ntype - row_start);
    const int nbins     = (1 << shift) * 2;
    const int grow0     = rowbase + row_start;

    const int nA = F.cntA[t], nB_ = F.cntB[t];
    const int nRuns = nA + nB_;

    // run directory: TL[b][chunk] / TL[b+1][chunk] contiguous u16 rows
    const unsigned short* __restrict__ TLb  = TL + (size_t)b * nchunksTot;
    const unsigned short* __restrict__ TLb1 = TL + (size_t)(b + 1) * nchunksTot;
    for (int i = tid; i < nRuns; i += 512) {
        int ci, base;
        if (i < nA) { ci = F.c0A[t] + i;        base = F.offA[t] + i * EPB; }
        else        { int k = i - nA;
                      ci = F.c0B[t] + k;        base = F.offB[t] + k * EPB; }
        const int s0 = (int)TLb[ci];
        runS[i] = base + s0;
        runL[i] = (unsigned short)((int)TLb1[ci] - s0);
    }
    if (tid < nbins) cnt[tid] = 0;
    __syncthreads();

    const int grp = tid >> 2;        // 128 groups of 4 lanes
    const int gl  = tid & 3;

    // pass 1: count fine bins (1B/edge)
    for (int ridx = grp; ridx < nRuns; ridx += 128) {
        const int rs = runS[ridx], re = rs + (int)runL[ridx];
        for (int j = rs + gl; j < re; j += 4) {
            atomicAdd(&cnt[binb[j]], 1);
        }
    }
    __syncthreads();

    // exclusive scan over nbins (<=256)
    const int v = (tid < nbins) ? cnt[tid] : 0;
    sh[tid] = v;
    __syncthreads();
    for (int off = 1; off < 512; off <<= 1) {
        const int x = (tid >= off) ? sh[tid - off] : 0;
        __syncthreads();
        sh[tid] += x;
        __syncthreads();
    }
    const int tot = sh[511];
    const bool staged = tot <= STCAP;
    const int excl = sh[tid] - v;
    if (tid < nbins) { cnt[tid] = excl; rowptr[tid] = excl; }
    if (tid == 0) {
        rowptr[nbins] = tot;
        if (!staged) fbOff = atomicAdd(fbCursor, tot);
    }
    __syncthreads();

    // pass 2: scatter payload to LDS stage (or global FB scratch)
    if (staged) {
        for (int ridx = grp; ridx < nRuns; ridx += 128) {
            const int rs = runS[ridx], re = rs + (int)runL[ridx];
            for (int j = rs + gl; j < re; j += 4) {
                const int pos = atomicAdd(&cnt[binb[j]], 1);
                stage[pos] = pay[j];
            }
        }
    } else {
        unsigned* fb = fbuf + fbOff;
        for (int ridx = grp; ridx < nRuns; ridx += 128) {
            const int rs = runS[ridx], re = rs + (int)runL[ridx];
            for (int j = rs + gl; j < re; j += 4) {
                const int pos = atomicAdd(&cnt[binb[j]], 1);
                fb[pos] = pay[j];
            }
        }
    }
    __syncthreads();

    // gather phase: 8 waves, rows strided by 8, off the staged segment
    const unsigned* seg = staged ? (const unsigned*)stage
                                 : (const unsigned*)(fbuf + fbOff);
    const int wave = tid >> 6;
    const int lane = tid & 63;
    const int g    = lane >> 3;
    const int li   = lane & 7;
    const int li4  = li * 4;
    const unsigned* srcUni = (t == 0) ? srcU : srcV;

    for (int r = wave; r < nrows; r += 8) {
        const int sA = rowptr[2 * r];
        const int eR = rowptr[2 * r + 2];
        float acc[8];
        #pragma unroll
        for (int k = 0; k < 8; ++k) acc[k] = 0.f;

        if (t < 2) {
            accum_seg(srcUni, seg, sA, eR, g, li4, acc);
        } else {
            const int sB = rowptr[2 * r + 1];
            accum_seg(srcFA, seg, sA, sB, g, li4, acc);
            accum_seg(srcFB, seg, sB, eR, g, li4, acc);
        }

        #pragma unroll
        for (int k = 0; k < 8; ++k) {
            acc[k] += __shfl_xor(acc[k], 8, 64);
            acc[k] += __shfl_xor(acc[k], 16, 64);
            acc[k] += __shfl_xor(acc[k], 32, 64);
        }
        if (g == 0) {
            float4 o0, o1;
            o0.x = fmaxf(acc[0], 0.f); o0.y = fmaxf(acc[1], 0.f);
            o0.z = fmaxf(acc[2], 0.f); o0.w = fmaxf(acc[3], 0.f);
            o1.x = fmaxf(acc[4], 0.f); o1.y = fmaxf(acc[5], 0.f);
            o1.z = fmaxf(acc[6], 0.f); o1.w = fmaxf(acc[7], 0.f);
            float4* dst = (float4*)(out + (size_t)(grow0 + r) * 64 + li * 8);
            dst[0] = o0;
            dst[1] = o1;
        }
    }
}

// ---------------------------------------------------------------------------
extern "C" void kernel_launch(void* const* d_in, const int* in_sizes, int n_in,
                              void* d_out, int out_size, void* d_ws, size_t ws_size,
                              hipStream_t stream)
{
    const float* x_u    = (const float*)d_in[0];
    const float* x_v    = (const float*)d_in[1];
    const float* x_f    = (const float*)d_in[2];
    const float* W_u_uv = (const float*)d_in[3];
    const float* W_v_uv = (const float*)d_in[4];
    const float* W_f2u  = (const float*)d_in[5];
    const float* W_f2v  = (const float*)d_in[6];
    const float* W_u2f  = (const float*)d_in[7];
    const float* W_v2f  = (const float*)d_in[8];

    const int* rows_[6] = {(const int*)d_in[9],  (const int*)d_in[12],
                           (const int*)d_in[15], (const int*)d_in[18],
                           (const int*)d_in[21], (const int*)d_in[24]};
    const int* cols_[6] = {(const int*)d_in[10], (const int*)d_in[13],
                           (const int*)d_in[16], (const int*)d_in[19],
                           (const int*)d_in[22], (const int*)d_in[25]};
    const float* vals_[6] = {(const float*)d_in[11], (const float*)d_in[14],
                             (const float*)d_in[17], (const float*)d_in[20],
                             (const float*)d_in[23], (const float*)d_in[26]};

    const int NU = in_sizes[0] / TDIM;
    const int NV = in_sizes[1] / TDIM;
    const int NF = in_sizes[2] / TDIM;
    const int E_[6] = {in_sizes[9], in_sizes[12], in_sizes[15],
                       in_sizes[18], in_sizes[21], in_sizes[24]};

    const int nbU = (NU + 127) >> 7;
    const int nbV = (NV + 127) >> 7;
    const int nbF = (NF + 31) >> 5;
    const int NB  = nbU + nbV + nbF;
    const int ntot_rows = NU + NV + NF;
    (void)ntot_rows;

    // u: rel0 uv (A=tmp_v), rel2 uf (B=f2u -> colp += NV)
    // v: rel1 vu (A=tmp_u), rel3 vf (B=f2v -> colp += NU)
    // f: rel4 fu (A=u2f),  rel5 fv (B=v2f)
    const int boff_[6]   = {0, nbU, 0, nbU, nbU + nbV, nbU + nbV};
    const int shift_[6]  = {7, 7, 7, 7, 5, 5};
    const int sflag_[6]  = {0, 0, 1, 1, 0, 1};
    const int coladd_[6] = {0, 0, NV, NU, 0, 0};

    size_t etot = 0;
    int eoff_[6];
    for (int r = 0; r < 6; ++r) { eoff_[r] = (int)etot; etot += (size_t)E_[r]; }

    // ---- relation pack / chunk map ----
    RelPack P;
    int nchunks = 0;
    int relchunks[6];
    for (int r = 0; r < 6; ++r) {
        P.r[r].rows = rows_[r]; P.r[r].cols = cols_[r]; P.r[r].vals = vals_[r];
        P.r[r].n = E_[r]; P.r[r].chunk0 = nchunks;
        P.r[r].boff = boff_[r]; P.r[r].shift = shift_[r]; P.r[r].srcflag = sflag_[r];
        P.r[r].eoff = eoff_[r]; P.r[r].coladd = coladd_[r];
        relchunks[r] = (E_[r] + EPB - 1) / EPB;
        nchunks += relchunks[r];
    }

    // ---- workspace ----
    char* wsb = (char*)d_ws;
    size_t o = 0;
    auto alloc = [&](size_t bytes) {
        char* p = wsb + o;
        o = (o + bytes + 15) & ~(size_t)15;
        return p;
    };
    // unified tables: [tmp_v | f2u] for u-gather, [tmp_u | f2v] for v-gather
    unsigned short* utab = (unsigned short*)alloc(((size_t)NV + NF) * TDIM * 2);
    unsigned short* vtab = (unsigned short*)alloc(((size_t)NU + NF) * TDIM * 2);
    unsigned short* u2f  = (unsigned short*)alloc((size_t)NU * TDIM * 2);
    unsigned short* v2f  = (unsigned short*)alloc((size_t)NV * TDIM * 2);
    unsigned short* tmp_v = utab;
    unsigned short* f2u   = utab + (size_t)NV * TDIM;
    unsigned short* tmp_u = vtab;
    unsigned short* f2v   = vtab + (size_t)NU * TDIM;
    unsigned short* localStart16 = (unsigned short*)alloc((size_t)nchunks * (NB + 1) * 2);
    unsigned short* TL16         = (unsigned short*)alloc((size_t)(NB + 1) * nchunks * 2);
    unsigned* pay        = (unsigned*)alloc(etot * 4);
    unsigned char* binb  = (unsigned char*)alloc(etot);
    unsigned* fbuf       = (unsigned*)alloc(etot * 4);
    int* fbCursor        = (int*)alloc(16);
    (void)ws_size;

    // ---- fused transforms ----
    TPack T;
    T.X[0] = x_u; T.W1[0] = W_u_uv; T.W2[0] = W_u2f; T.Y1[0] = tmp_u; T.Y2[0] = u2f; T.N[0] = NU;
    T.X[1] = x_v; T.W1[1] = W_v_uv; T.W2[1] = W_v2f; T.Y1[1] = tmp_v; T.Y2[1] = v2f; T.N[1] = NV;
    T.X[2] = x_f; T.W1[2] = W_f2u;  T.W2[2] = W_f2v; T.Y1[2] = f2u;  T.Y2[2] = f2v; T.N[2] = NF;
    T.c0[0] = 0;
    T.c0[1] = (NU + 63) / 64;
    T.c0[2] = T.c0[1] + (NV + 63) / 64;
    const int tchunks = T.c0[2] + (NF + 63) / 64;
    transform_fused_kernel<<<tchunks, 256, 0, stream>>>(T);

    // ---- sort pipeline ----
    hipMemsetAsync(fbCursor, 0, sizeof(int), stream);
    bucketize_cm_kernel<<<nchunks, 512, 0, stream>>>(P, pay, binb, localStart16, NB);
    {
        dim3 tgrid((NB + 1 + 31) / 32, (nchunks + 31) / 32);
        transpose16_kernel<<<tgrid, 256, 0, stream>>>(localStart16, TL16, nchunks, NB + 1);
    }

    FSPack F;
    const int Arel[3] = {0, 1, 4}, Brel[3] = {2, 3, 5};
    for (int t = 0; t < 3; ++t) {
        F.c0A[t] = P.r[Arel[t]].chunk0; F.cntA[t] = relchunks[Arel[t]]; F.offA[t] = eoff_[Arel[t]];
        F.c0B[t] = P.r[Brel[t]].chunk0; F.cntB[t] = relchunks[Brel[t]]; F.offB[t] = eoff_[Brel[t]];
    }

    // ---- fused finesort + gather (+ReLU) ----
    finesort_gather_kernel<<<NB, 512, 0, stream>>>(
        pay, binb, TL16, F,
        (const unsigned*)utab, (const unsigned*)vtab,
        (const unsigned*)u2f,  (const unsigned*)v2f,
        fbuf, fbCursor, (float*)d_out,
        nbU, nbV, NU, NV, NF, NB, nchunks);
}